// Round 1
// baseline (761.529 us; speedup 1.0000x reference)
//
#include <hip/hip_runtime.h>
#include <math.h>

#define B_ 16
#define M_ 2048
#define C_ 128
#define NT_ 32   // M_/64

using f4 = float4;

// ---------------------------------------------------------------- sq[b,i] = sum_c x^2
__global__ __launch_bounds__(256) void sq_kernel(const float* __restrict__ x,
                                                 float* __restrict__ sq) {
    int row  = blockIdx.x * 4 + (threadIdx.x >> 6);   // 4 waves/block, wave per row
    int lane = threadIdx.x & 63;
    const float* xr = x + (size_t)row * C_;
    float a = xr[lane], b = xr[lane + 64];
    float v = a * a + b * b;
    #pragma unroll
    for (int o = 32; o; o >>= 1) v += __shfl_down(v, o);
    if (lane == 0) sq[row] = v;
}

// ---------------------------------------------------------------- triangular Gram tiles
// MODE 0: accumulate off-diagonal sqrt(d2) sums -> off_part[b][ti][tj] (double)
// MODE 1: accumulate exp(-d2*inv2h2) row/col sums -> rho_part[b*M+i][tslot] (float)
// LDS: two 64x128 f32 tiles, XOR-swizzled float4 slots (slot = c4 ^ (row&31)) -> 64KB, no pad.
template <int MODE>
__global__ __launch_bounds__(256, 2) void gram_kernel(
    const float* __restrict__ x, const float* __restrict__ sq,
    const float* __restrict__ invh,
    double* __restrict__ off_part, float* __restrict__ rho_part) {
    int ti = blockIdx.x, tj = blockIdx.y, b = blockIdx.z;
    if (tj < ti) return;                       // triangular: uniform early exit
    __shared__ f4 A4[64][32];
    __shared__ f4 B4[64][32];
    const float* xb = x + (size_t)b * M_ * C_;
    int i0 = ti * 64, j0 = tj * 64;
    int tid = threadIdx.x;
    for (int s = tid; s < 64 * 32; s += 256) {
        int row = s >> 5, c4 = s & 31;
        A4[row][c4 ^ (row & 31)] = ((const f4*)(xb + (size_t)(i0 + row) * C_))[c4];
        B4[row][c4 ^ (row & 31)] = ((const f4*)(xb + (size_t)(j0 + row) * C_))[c4];
    }
    __syncthreads();
    int tx = tid & 15, ty = tid >> 4;          // i = ty+16*di, j = tx+16*dj
    float acc[4][4] = {};
    #pragma unroll 4
    for (int k4 = 0; k4 < 32; ++k4) {
        f4 a[4], w[4];
        #pragma unroll
        for (int d = 0; d < 4; ++d) {
            int ri = ty + 16 * d;
            a[d] = A4[ri][k4 ^ (ri & 31)];
            int rj = tx + 16 * d;
            w[d] = B4[rj][k4 ^ (rj & 31)];
        }
        #pragma unroll
        for (int di = 0; di < 4; ++di)
            #pragma unroll
            for (int dj = 0; dj < 4; ++dj)
                acc[di][dj] += a[di].x * w[dj].x + a[di].y * w[dj].y +
                               a[di].z * w[dj].z + a[di].w * w[dj].w;
    }
    float sqi[4], sqj[4];
    #pragma unroll
    for (int d = 0; d < 4; ++d) {
        sqi[d] = sq[b * M_ + i0 + ty + 16 * d];
        sqj[d] = sq[b * M_ + j0 + tx + 16 * d];
    }
    if (MODE == 0) {
        float part = 0.f;
        #pragma unroll
        for (int di = 0; di < 4; ++di)
            #pragma unroll
            for (int dj = 0; dj < 4; ++dj) {
                float d2   = sqi[di] + sqj[dj] - 2.f * acc[di][dj];
                float dist = sqrtf(fmaxf(d2, 1e-12f));
                if (ti == tj) { if ((ty + 16 * di) != (tx + 16 * dj)) part += dist; }
                else part += 2.f * dist;       // each unordered pair counted twice
            }
        #pragma unroll
        for (int o = 32; o; o >>= 1) part += __shfl_down(part, o);
        __syncthreads();
        double* red = (double*)&A4[0][0];      // reuse LDS
        if ((tid & 63) == 0) red[tid >> 6] = (double)part;
        __syncthreads();
        if (tid == 0)
            off_part[((size_t)b << 10) + ti * 32 + tj] = red[0] + red[1] + red[2] + red[3];
    } else {
        float s = invh[b];
        float rs[4] = {0, 0, 0, 0}, cs[4] = {0, 0, 0, 0};
        #pragma unroll
        for (int di = 0; di < 4; ++di)
            #pragma unroll
            for (int dj = 0; dj < 4; ++dj) {
                float d2 = sqi[di] + sqj[dj] - 2.f * acc[di][dj];
                float e  = __expf(-fmaxf(d2, 1e-12f) * s);   // diag: d2c=1e-12 -> e=1 (matches ref)
                rs[di] += e; cs[dj] += e;
            }
        #pragma unroll
        for (int di = 0; di < 4; ++di) {
            #pragma unroll
            for (int o = 1; o < 16; o <<= 1) rs[di] += __shfl_xor(rs[di], o);  // over tx group
        }
        if (tx == 0) {
            #pragma unroll
            for (int di = 0; di < 4; ++di)
                rho_part[((size_t)(b * M_ + i0 + ty + 16 * di) << 5) + tj] = rs[di];
        }
        if (ti != tj) {                        // mirrored contribution for rows of Tj
            #pragma unroll
            for (int dj = 0; dj < 4; ++dj) {
                #pragma unroll
                for (int o = 16; o < 64; o <<= 1) cs[dj] += __shfl_xor(cs[dj], o); // over ty-in-wave
            }
            __syncthreads();
            float* cred = (float*)&A4[0][0];   // [wave][64], deterministic cross-wave reduce
            int lane = tid & 63, wv = tid >> 6;
            if (lane < 16) {
                #pragma unroll
                for (int dj = 0; dj < 4; ++dj) cred[wv * 64 + lane + 16 * dj] = cs[dj];
            }
            __syncthreads();
            if (tid < 64) {
                float v = cred[tid] + cred[64 + tid] + cred[128 + tid] + cred[192 + tid];
                rho_part[((size_t)(b * M_ + j0 + tid) << 5) + ti] = v;
            }
        }
    }
}

// ---------------------------------------------------------------- h -> inv2h2 per batch
__global__ __launch_bounds__(256) void offreduce_kernel(const double* __restrict__ off_part,
                                                        float* __restrict__ invh) {
    int b = blockIdx.x, tid = threadIdx.x;
    double s = 0.0;
    for (int q = tid; q < 1024; q += 256) {
        int ti = q >> 5, tj = q & 31;
        if (tj >= ti) s += off_part[((size_t)b << 10) + q];
    }
    __shared__ double red[256];
    red[tid] = s; __syncthreads();
    for (int o = 128; o; o >>= 1) { if (tid < o) red[tid] += red[tid + o]; __syncthreads(); }
    if (tid == 0) {
        double h = red[0] / ((double)M_ * (double)(M_ - 1));
        h = h > 1e-6 ? h : 1e-6;
        invh[b] = (float)(1.0 / (2.0 * h * h));
    }
}

// ---------------------------------------------------------------- rho = fixed-order sum of 32 partials
__global__ __launch_bounds__(256) void rho_reduce(const float* __restrict__ part,
                                                  float* __restrict__ rho) {
    int i = blockIdx.x * 256 + threadIdx.x;
    const float* p = part + ((size_t)i << 5);
    float s = 0.f;
    #pragma unroll
    for (int t = 0; t < 32; ++t) s += p[t];
    rho[i] = s;
}

// ---------------------------------------------------------------- rank + scatter permutation
__global__ __launch_bounds__(256) void rank_kernel(const float* __restrict__ rho,
                                                   int* __restrict__ perm) {
    int b = blockIdx.y;
    int i = blockIdx.x * 256 + threadIdx.x;
    __shared__ float r[M_];
    const float* rb = rho + b * M_;
    for (int t = threadIdx.x; t < M_; t += 256) r[t] = rb[t];
    __syncthreads();
    float rv = r[i];
    int cnt = 0;
    for (int j = 0; j < M_; ++j) {
        float o = r[j];
        cnt += (o < rv || (o == rv && j < i)) ? 1 : 0;   // index tie-break -> valid perm
    }
    perm[b * M_ + cnt] = i;
}

// ---------------------------------------------------------------- g_t = sum_{s<=t} 1/(M-s); dvs_t = 1/sqrt(t+1)
__global__ __launch_bounds__(256) void g_kernel(float* __restrict__ g, float* __restrict__ dvs) {
    int tid = threadIdx.x;
    __shared__ double w[256];
    double loc = 0.0;
    #pragma unroll
    for (int q = 0; q < 8; ++q) loc += 1.0 / (double)(M_ - (tid * 8 + q));
    w[tid] = loc; __syncthreads();
    for (int o = 1; o < 256; o <<= 1) {
        double v = (tid >= o) ? w[tid - o] : 0.0;
        __syncthreads();
        w[tid] += v;
        __syncthreads();
    }
    double acc = (tid > 0) ? w[tid - 1] : 0.0;
    #pragma unroll
    for (int q = 0; q < 8; ++q) {
        int t = tid * 8 + q;
        acc += 1.0 / (double)(M_ - t);
        g[t]   = (float)acc;
        dvs[t] = (float)(1.0 / sqrt((double)(t + 1)));
    }
}

// ---------------------------------------------------------------- per-chunk partial sums of u and g*u
__global__ __launch_bounds__(128) void scan_chunk(
    const float* __restrict__ x, const int* __restrict__ perm,
    const float* __restrict__ g, const float* __restrict__ dvs,
    double* __restrict__ chunkU, double* __restrict__ chunkGU) {
    int b = blockIdx.x, ch = blockIdx.y, c = threadIdx.x;
    __shared__ int   pidx[128];
    __shared__ float gl[128], dl[128];
    int t0 = ch * 128;
    pidx[c] = perm[b * M_ + t0 + c];
    gl[c]   = g[t0 + c];
    dl[c]   = dvs[t0 + c];
    __syncthreads();
    const float* xb = x + (size_t)b * M_ * C_;
    double sU = 0.0, sGU = 0.0;
    for (int tt = 0; tt < 128; ++tt) {
        double u = (double)xb[(size_t)pidx[tt] * C_ + c] * (double)dl[tt];
        sU  += u;
        sGU += (double)gl[tt] * u;
    }
    chunkU [(size_t)(b * 16 + ch) * 128 + c] = sU;
    chunkGU[(size_t)(b * 16 + ch) * 128 + c] = sGU;
}

// ---------------------------------------------------------------- y_{p_t} = dvs_t*(g_t*(Utot-U(t)) + P(t))
__global__ __launch_bounds__(128) void scan_final(
    const float* __restrict__ x, const int* __restrict__ perm,
    const float* __restrict__ g, const float* __restrict__ dvs,
    const double* __restrict__ chunkU, const double* __restrict__ chunkGU,
    float* __restrict__ y) {
    int b = blockIdx.x, ch = blockIdx.y, c = threadIdx.x;
    __shared__ int   pidx[128];
    __shared__ float gl[128], dl[128];
    int t0 = ch * 128;
    pidx[c] = perm[b * M_ + t0 + c];
    gl[c]   = g[t0 + c];
    dl[c]   = dvs[t0 + c];
    __syncthreads();
    double Utot = 0.0, runU = 0.0, runG = 0.0;
    for (int q = 0; q < 16; ++q) {
        double cu = chunkU[(size_t)(b * 16 + q) * 128 + c];
        Utot += cu;
        if (q < ch) { runU += cu; runG += chunkGU[(size_t)(b * 16 + q) * 128 + c]; }
    }
    const float* xb = x + (size_t)b * M_ * C_;
    float*       yb = y + (size_t)b * M_ * C_;
    for (int tt = 0; tt < 128; ++tt) {
        int idx = pidx[tt];
        double u  = (double)xb[(size_t)idx * C_ + c] * (double)dl[tt];
        double yv = (double)dl[tt] * ((double)gl[tt] * (Utot - runU) + runG);
        yb[(size_t)idx * C_ + c] = (float)yv;
        runU += u;
        runG += (double)gl[tt] * u;
    }
}

// ---------------------------------------------------------------- out = SiLU(y @ W^T), in-place on d_out
__global__ __launch_bounds__(256, 2) void linear_silu(float* __restrict__ y,
                                                      const float* __restrict__ W) {
    int b = blockIdx.y, m0 = blockIdx.x * 64;
    __shared__ f4 Y4[64][32];
    __shared__ f4 W4[64][32];
    float* yb = y + ((size_t)b * M_ + m0) * C_;
    int tid = threadIdx.x;
    for (int s = tid; s < 64 * 32; s += 256) {   // stage y BEFORE any write (in-place safe)
        int row = s >> 5, c4 = s & 31;
        Y4[row][c4 ^ (row & 31)] = ((const f4*)(yb + (size_t)row * C_))[c4];
    }
    int tx = tid & 15, ty = tid >> 4;
    for (int half = 0; half < 2; ++half) {
        __syncthreads();                         // Y4 staged / previous W4 reads done
        for (int s = tid; s < 64 * 32; s += 256) {
            int row = s >> 5, c4 = s & 31;
            W4[row][c4 ^ (row & 31)] = ((const f4*)(W + (size_t)(half * 64 + row) * C_))[c4];
        }
        __syncthreads();
        float acc[4][4] = {};
        #pragma unroll 4
        for (int k4 = 0; k4 < 32; ++k4) {
            f4 a[4], w[4];
            #pragma unroll
            for (int d = 0; d < 4; ++d) {
                int rm = ty + 16 * d;
                a[d] = Y4[rm][k4 ^ (rm & 31)];
                int rc = tx + 16 * d;
                w[d] = W4[rc][k4 ^ (rc & 31)];
            }
            #pragma unroll
            for (int di = 0; di < 4; ++di)
                #pragma unroll
                for (int dj = 0; dj < 4; ++dj)
                    acc[di][dj] += a[di].x * w[dj].x + a[di].y * w[dj].y +
                                   a[di].z * w[dj].z + a[di].w * w[dj].w;
        }
        #pragma unroll
        for (int di = 0; di < 4; ++di)
            #pragma unroll
            for (int dj = 0; dj < 4; ++dj) {
                int m = ty + 16 * di, co = half * 64 + tx + 16 * dj;
                float v = acc[di][dj];
                yb[(size_t)m * C_ + co] = v / (1.f + __expf(-v));   // SiLU
            }
    }
}

// ----------------------------------------------------------------
extern "C" void kernel_launch(void* const* d_in, const int* in_sizes, int n_in,
                              void* d_out, int out_size, void* d_ws, size_t ws_size,
                              hipStream_t stream) {
    (void)in_sizes; (void)n_in; (void)out_size; (void)ws_size;
    const float* x = (const float*)d_in[0];
    const float* W = (const float*)d_in[1];
    float* out = (float*)d_out;

    char* ws = (char*)d_ws;
    size_t o = 0;
    auto alloc = [&](size_t n) { size_t r = o; o += (n + 255) & ~(size_t)255; return r; };
    double* off_part = (double*)(ws + alloc((size_t)B_ * 1024 * 8));     // 128KB
    float*  invh     = (float*) (ws + alloc(B_ * 4));
    float*  sqv      = (float*) (ws + alloc((size_t)B_ * M_ * 4));       // 128KB
    float*  rho      = (float*) (ws + alloc((size_t)B_ * M_ * 4));       // 128KB
    int*    perm     = (int*)   (ws + alloc((size_t)B_ * M_ * 4));       // 128KB
    float*  g        = (float*) (ws + alloc(M_ * 4));
    float*  dvs      = (float*) (ws + alloc(M_ * 4));
    double* chunkU   = (double*)(ws + alloc((size_t)B_ * 16 * C_ * 8));  // 256KB
    double* chunkGU  = (double*)(ws + alloc((size_t)B_ * 16 * C_ * 8));  // 256KB
    // rho_part (4MB) lives in the front of d_out; consumed before y is written.
    float* rho_part = out;

    sq_kernel<<<(B_ * M_) / 4, 256, 0, stream>>>(x, sqv);
    gram_kernel<0><<<dim3(NT_, NT_, B_), 256, 0, stream>>>(x, sqv, nullptr, off_part, nullptr);
    offreduce_kernel<<<B_, 256, 0, stream>>>(off_part, invh);
    gram_kernel<1><<<dim3(NT_, NT_, B_), 256, 0, stream>>>(x, sqv, invh, nullptr, rho_part);
    rho_reduce<<<(B_ * M_) / 256, 256, 0, stream>>>(rho_part, rho);
    rank_kernel<<<dim3(M_ / 256, B_), 256, 0, stream>>>(rho, perm);
    g_kernel<<<1, 256, 0, stream>>>(g, dvs);
    scan_chunk<<<dim3(B_, 16), 128, 0, stream>>>(x, perm, g, dvs, chunkU, chunkGU);
    scan_final<<<dim3(B_, 16), 128, 0, stream>>>(x, perm, g, dvs, chunkU, chunkGU, out);
    linear_silu<<<dim3(M_ / 64, B_), 256, 0, stream>>>(out, W);
}

// Round 2
// 372.505 us; speedup vs baseline: 2.0443x; 2.0443x over previous
//
#include <hip/hip_runtime.h>
#include <math.h>

#define B_ 16
#define M_ 2048
#define C_ 128

using f4 = float4;
typedef __attribute__((ext_vector_type(8))) short bf16x8;
typedef __attribute__((ext_vector_type(16))) float f32x16;

// round-to-nearest-even f32 -> bf16 bits
__device__ inline unsigned short bfr(float f) {
    unsigned int u = __float_as_uint(f);
    return (unsigned short)((u + 0x7FFFu + ((u >> 16) & 1u)) >> 16);
}

// ---------------------------------------------------------------- sq[b,i] = sum_c x^2
__global__ __launch_bounds__(256) void sq_kernel(const float* __restrict__ x,
                                                 float* __restrict__ sq) {
    int row  = blockIdx.x * 4 + (threadIdx.x >> 6);
    int lane = threadIdx.x & 63;
    const float* xr = x + (size_t)row * C_;
    float a = xr[lane], b = xr[lane + 64];
    float v = a * a + b * b;
    #pragma unroll
    for (int o = 32; o; o >>= 1) v += __shfl_down(v, o);
    if (lane == 0) sq[row] = v;
}

// ---------------------------------------------------------------- MFMA Gram, 128x128 tiles
// MODE 0: hi*hi only -> off-diag sqrt(d2) sums  -> off_part[b][ti*16+tj]
// MODE 1: hi*hi+hi*lo+lo*hi -> exp(-d2*s) row/col partial sums -> rho_part[point][32]
// LDS tiles: [128 rows][16 chunks of 16B] bf16, chunk swizzle c ^= (row&15).
template <int MODE>
__global__ __launch_bounds__(256) void gram_mfma(
    const float* __restrict__ x, const float* __restrict__ sq,
    const float* __restrict__ invh,
    double* __restrict__ off_part, float* __restrict__ rho_part) {
    int ti = blockIdx.x, tj = blockIdx.y, b = blockIdx.z;
    if (tj < ti) return;
    constexpr int LDSB = (MODE == 1) ? 131072 : 65536;
    __shared__ __align__(16) char lds[LDSB];
    const bool diag = (ti == tj);
    constexpr int offAhi = 0;
    constexpr int offAlo = 32768;                         // MODE1 only
    const int offBhi = (MODE == 1) ? (diag ? 0 : 65536) : (diag ? 0 : 32768);
    const int offBlo = diag ? 32768 : 98304;              // MODE1 only
    int tid = threadIdx.x;

    const float* srcA = x + ((size_t)b * M_ + ti * 128) * C_;
    const float* srcB = x + ((size_t)b * M_ + tj * 128) * C_;

    auto stage = [&](const float* src, int offHi, int offLo) {
        #pragma unroll 4
        for (int q = 0; q < 16; ++q) {
            int s = tid + (q << 8);                       // 0..4095 float4-chunks
            int row = s >> 5, c4 = s & 31;
            f4 v = *(const f4*)(src + (size_t)row * C_ + (c4 << 2));
            unsigned short h0 = bfr(v.x), h1 = bfr(v.y), h2 = bfr(v.z), h3 = bfr(v.w);
            int base = row * 256 + ((((c4 >> 1) ^ (row & 15)) << 4)) + ((c4 & 1) << 3);
            uint2 hp;
            hp.x = (unsigned)h0 | ((unsigned)h1 << 16);
            hp.y = (unsigned)h2 | ((unsigned)h3 << 16);
            *(uint2*)(lds + offHi + base) = hp;
            if (MODE == 1) {
                float r0 = v.x - __uint_as_float((unsigned)h0 << 16);
                float r1 = v.y - __uint_as_float((unsigned)h1 << 16);
                float r2 = v.z - __uint_as_float((unsigned)h2 << 16);
                float r3 = v.w - __uint_as_float((unsigned)h3 << 16);
                unsigned short l0 = bfr(r0), l1 = bfr(r1), l2 = bfr(r2), l3 = bfr(r3);
                uint2 lp;
                lp.x = (unsigned)l0 | ((unsigned)l1 << 16);
                lp.y = (unsigned)l2 | ((unsigned)l3 << 16);
                *(uint2*)(lds + offLo + base) = lp;
            }
        }
    };
    stage(srcA, offAhi, offAlo);
    if (!diag) stage(srcB, (MODE == 1) ? 65536 : 32768, 98304);
    __syncthreads();

    int lane = tid & 63, wid = tid >> 6;
    int wr = wid >> 1, wc = wid & 1;                      // 2x2 waves of 64x64
    int l31 = lane & 31, l5 = lane >> 5;

    f32x16 acc[2][2] = {};
    auto frag = [&](int off, int rowblk, int ks) -> bf16x8 {
        int row = rowblk + l31;
        int c = ((ks << 1) | l5) ^ (row & 15);
        return *(const bf16x8*)(lds + off + row * 256 + (c << 4));
    };
    #pragma unroll
    for (int ks = 0; ks < 8; ++ks) {
        bf16x8 ah0 = frag(offAhi, wr * 64, ks),      ah1 = frag(offAhi, wr * 64 + 32, ks);
        bf16x8 bh0 = frag(offBhi, wc * 64, ks),      bh1 = frag(offBhi, wc * 64 + 32, ks);
        acc[0][0] = __builtin_amdgcn_mfma_f32_32x32x16_bf16(ah0, bh0, acc[0][0], 0, 0, 0);
        acc[0][1] = __builtin_amdgcn_mfma_f32_32x32x16_bf16(ah0, bh1, acc[0][1], 0, 0, 0);
        acc[1][0] = __builtin_amdgcn_mfma_f32_32x32x16_bf16(ah1, bh0, acc[1][0], 0, 0, 0);
        acc[1][1] = __builtin_amdgcn_mfma_f32_32x32x16_bf16(ah1, bh1, acc[1][1], 0, 0, 0);
        if (MODE == 1) {
            bf16x8 al0 = frag(offAlo, wr * 64, ks),  al1 = frag(offAlo, wr * 64 + 32, ks);
            bf16x8 bl0 = frag(offBlo, wc * 64, ks),  bl1 = frag(offBlo, wc * 64 + 32, ks);
            acc[0][0] = __builtin_amdgcn_mfma_f32_32x32x16_bf16(ah0, bl0, acc[0][0], 0, 0, 0);
            acc[0][1] = __builtin_amdgcn_mfma_f32_32x32x16_bf16(ah0, bl1, acc[0][1], 0, 0, 0);
            acc[1][0] = __builtin_amdgcn_mfma_f32_32x32x16_bf16(ah1, bl0, acc[1][0], 0, 0, 0);
            acc[1][1] = __builtin_amdgcn_mfma_f32_32x32x16_bf16(ah1, bl1, acc[1][1], 0, 0, 0);
            acc[0][0] = __builtin_amdgcn_mfma_f32_32x32x16_bf16(al0, bh0, acc[0][0], 0, 0, 0);
            acc[0][1] = __builtin_amdgcn_mfma_f32_32x32x16_bf16(al0, bh1, acc[0][1], 0, 0, 0);
            acc[1][0] = __builtin_amdgcn_mfma_f32_32x32x16_bf16(al1, bh0, acc[1][0], 0, 0, 0);
            acc[1][1] = __builtin_amdgcn_mfma_f32_32x32x16_bf16(al1, bh1, acc[1][1], 0, 0, 0);
        }
    }

    // C/D layout (m74/m101): col = lane&31, row = (reg&3) + 8*(reg>>2) + 4*(lane>>5)
    int i0 = ti * 128 + wr * 64, j0 = tj * 128 + wc * 64;
    float sqj0 = sq[b * M_ + j0 + l31];
    float sqj1 = sq[b * M_ + j0 + 32 + l31];

    if (MODE == 0) {
        float part = 0.f;
        #pragma unroll
        for (int fi = 0; fi < 2; ++fi)
            #pragma unroll
            for (int rg = 0; rg < 16; ++rg) {
                int rin = (rg & 3) + ((rg >> 2) << 3) + (l5 << 2);
                float si = sq[b * M_ + i0 + fi * 32 + rin];
                float d20 = si + sqj0 - 2.f * acc[fi][0][rg];
                float d21 = si + sqj1 - 2.f * acc[fi][1][rg];
                float ds0 = sqrtf(fmaxf(d20, 1e-12f));
                float ds1 = sqrtf(fmaxf(d21, 1e-12f));
                if (diag) {
                    bool dg0 = (wr == wc) && (fi == 0) && (rin == l31);
                    bool dg1 = (wr == wc) && (fi == 1) && (rin == l31);
                    part += (dg0 ? 0.f : ds0) + (dg1 ? 0.f : ds1);
                } else {
                    part += 2.f * (ds0 + ds1);
                }
            }
        #pragma unroll
        for (int m = 1; m < 64; m <<= 1) part += __shfl_xor(part, m);
        __syncthreads();
        double* red = (double*)lds;
        if (lane == 0) red[wid] = (double)part;
        __syncthreads();
        if (tid == 0)
            off_part[b * 256 + ti * 16 + tj] = red[0] + red[1] + red[2] + red[3];
    } else {
        float s = invh[b];
        float rs[2][16];
        float cs0 = 0.f, cs1 = 0.f;
        #pragma unroll
        for (int fi = 0; fi < 2; ++fi)
            #pragma unroll
            for (int rg = 0; rg < 16; ++rg) {
                int rin = (rg & 3) + ((rg >> 2) << 3) + (l5 << 2);
                float si = sq[b * M_ + i0 + fi * 32 + rin];
                float e0 = __expf(-fmaxf(si + sqj0 - 2.f * acc[fi][0][rg], 1e-12f) * s);
                float e1 = __expf(-fmaxf(si + sqj1 - 2.f * acc[fi][1][rg], 1e-12f) * s);
                rs[fi][rg] = e0 + e1;
                cs0 += e0; cs1 += e1;
            }
        // row sums: reduce over the 32-lane col group (masks 1..16)
        #pragma unroll
        for (int fi = 0; fi < 2; ++fi)
            #pragma unroll
            for (int rg = 0; rg < 16; ++rg) {
                float v = rs[fi][rg];
                #pragma unroll
                for (int m = 1; m < 32; m <<= 1) v += __shfl_xor(v, m);
                rs[fi][rg] = v;
            }
        if (l31 == 0) {
            #pragma unroll
            for (int fi = 0; fi < 2; ++fi)
                #pragma unroll
                for (int rg = 0; rg < 16; ++rg) {
                    int rin = (rg & 3) + ((rg >> 2) << 3) + (l5 << 2);
                    rho_part[(size_t)(b * M_ + i0 + fi * 32 + rin) * 32 + tj * 2 + wc] =
                        rs[fi][rg];
                }
        }
        // col sums: per-thread (over reg,fi) done; fold the two 32-lane halves
        cs0 += __shfl_xor(cs0, 32);
        cs1 += __shfl_xor(cs1, 32);
        if (!diag && lane < 32) {
            rho_part[(size_t)(b * M_ + j0 + l31) * 32 + ti * 2 + wr] = cs0;
            rho_part[(size_t)(b * M_ + j0 + 32 + l31) * 32 + ti * 2 + wr] = cs1;
        }
    }
}

// ---------------------------------------------------------------- h -> 1/(2h^2) per batch
__global__ __launch_bounds__(256) void offreduce_kernel(const double* __restrict__ off_part,
                                                        float* __restrict__ invh) {
    int b = blockIdx.x, tid = threadIdx.x;
    int ti = tid >> 4, tj = tid & 15;
    double s = (tj >= ti) ? off_part[b * 256 + tid] : 0.0;
    __shared__ double red[256];
    red[tid] = s; __syncthreads();
    for (int o = 128; o; o >>= 1) { if (tid < o) red[tid] += red[tid + o]; __syncthreads(); }
    if (tid == 0) {
        double h = red[0] / ((double)M_ * (double)(M_ - 1));
        h = h > 1e-6 ? h : 1e-6;
        invh[b] = (float)(1.0 / (2.0 * h * h));
    }
}

// ---------------------------------------------------------------- rho = fixed-order sum of 32 partials
__global__ __launch_bounds__(256) void rho_reduce(const float* __restrict__ part,
                                                  float* __restrict__ rho) {
    int i = blockIdx.x * 256 + threadIdx.x;
    const float* p = part + ((size_t)i << 5);
    float s = 0.f;
    #pragma unroll
    for (int t = 0; t < 32; ++t) s += p[t];
    rho[i] = s;
}

// ---------------------------------------------------------------- rank + scatter permutation
__global__ __launch_bounds__(256) void rank_kernel(const float* __restrict__ rho,
                                                   int* __restrict__ perm) {
    int b = blockIdx.y;
    int i = blockIdx.x * 256 + threadIdx.x;
    __shared__ float r[M_];
    const float* rb = rho + b * M_;
    for (int t = threadIdx.x; t < M_; t += 256) r[t] = rb[t];
    __syncthreads();
    float rv = r[i];
    int cnt = 0;
    for (int j = 0; j < M_; ++j) {
        float o = r[j];
        cnt += (o < rv || (o == rv && j < i)) ? 1 : 0;
    }
    perm[b * M_ + cnt] = i;
}

// ---------------------------------------------------------------- g_t, dvs_t tables
__global__ __launch_bounds__(256) void g_kernel(float* __restrict__ g, float* __restrict__ dvs) {
    int tid = threadIdx.x;
    __shared__ double w[256];
    double loc = 0.0;
    #pragma unroll
    for (int q = 0; q < 8; ++q) loc += 1.0 / (double)(M_ - (tid * 8 + q));
    w[tid] = loc; __syncthreads();
    for (int o = 1; o < 256; o <<= 1) {
        double v = (tid >= o) ? w[tid - o] : 0.0;
        __syncthreads();
        w[tid] += v;
        __syncthreads();
    }
    double acc = (tid > 0) ? w[tid - 1] : 0.0;
    #pragma unroll
    for (int q = 0; q < 8; ++q) {
        int t = tid * 8 + q;
        acc += 1.0 / (double)(M_ - t);
        g[t]   = (float)acc;
        dvs[t] = (float)(1.0 / sqrt((double)(t + 1)));
    }
}

// ---------------------------------------------------------------- per-chunk partial sums
__global__ __launch_bounds__(128) void scan_chunk(
    const float* __restrict__ x, const int* __restrict__ perm,
    const float* __restrict__ g, const float* __restrict__ dvs,
    double* __restrict__ chunkU, double* __restrict__ chunkGU) {
    int b = blockIdx.x, ch = blockIdx.y, c = threadIdx.x;
    __shared__ int   pidx[128];
    __shared__ float gl[128], dl[128];
    int t0 = ch * 128;
    pidx[c] = perm[b * M_ + t0 + c];
    gl[c]   = g[t0 + c];
    dl[c]   = dvs[t0 + c];
    __syncthreads();
    const float* xb = x + (size_t)b * M_ * C_;
    double sU = 0.0, sGU = 0.0;
    for (int tt = 0; tt < 128; ++tt) {
        double u = (double)xb[(size_t)pidx[tt] * C_ + c] * (double)dl[tt];
        sU  += u;
        sGU += (double)gl[tt] * u;
    }
    chunkU [(size_t)(b * 16 + ch) * 128 + c] = sU;
    chunkGU[(size_t)(b * 16 + ch) * 128 + c] = sGU;
}

// ---------------------------------------------------------------- y via two prefix scans
__global__ __launch_bounds__(128) void scan_final(
    const float* __restrict__ x, const int* __restrict__ perm,
    const float* __restrict__ g, const float* __restrict__ dvs,
    const double* __restrict__ chunkU, const double* __restrict__ chunkGU,
    float* __restrict__ y) {
    int b = blockIdx.x, ch = blockIdx.y, c = threadIdx.x;
    __shared__ int   pidx[128];
    __shared__ float gl[128], dl[128];
    int t0 = ch * 128;
    pidx[c] = perm[b * M_ + t0 + c];
    gl[c]   = g[t0 + c];
    dl[c]   = dvs[t0 + c];
    __syncthreads();
    double Utot = 0.0, runU = 0.0, runG = 0.0;
    for (int q = 0; q < 16; ++q) {
        double cu = chunkU[(size_t)(b * 16 + q) * 128 + c];
        Utot += cu;
        if (q < ch) { runU += cu; runG += chunkGU[(size_t)(b * 16 + q) * 128 + c]; }
    }
    const float* xb = x + (size_t)b * M_ * C_;
    float*       yb = y + (size_t)b * M_ * C_;
    for (int tt = 0; tt < 128; ++tt) {
        int idx = pidx[tt];
        double u  = (double)xb[(size_t)idx * C_ + c] * (double)dl[tt];
        double yv = (double)dl[tt] * ((double)gl[tt] * (Utot - runU) + runG);
        yb[(size_t)idx * C_ + c] = (float)yv;
        runU += u;
        runG += (double)gl[tt] * u;
    }
}

// ---------------------------------------------------------------- out = SiLU(y @ W^T), in-place
__global__ __launch_bounds__(256, 2) void linear_silu(float* __restrict__ y,
                                                      const float* __restrict__ W) {
    int b = blockIdx.y, m0 = blockIdx.x * 64;
    __shared__ f4 Y4[64][32];
    __shared__ f4 W4[64][32];
    float* yb = y + ((size_t)b * M_ + m0) * C_;
    int tid = threadIdx.x;
    for (int s = tid; s < 64 * 32; s += 256) {
        int row = s >> 5, c4 = s & 31;
        Y4[row][c4 ^ (row & 31)] = ((const f4*)(yb + (size_t)row * C_))[c4];
    }
    int tx = tid & 15, ty = tid >> 4;
    for (int half = 0; half < 2; ++half) {
        __syncthreads();
        for (int s = tid; s < 64 * 32; s += 256) {
            int row = s >> 5, c4 = s & 31;
            W4[row][c4 ^ (row & 31)] = ((const f4*)(W + (size_t)(half * 64 + row) * C_))[c4];
        }
        __syncthreads();
        float acc[4][4] = {};
        #pragma unroll 4
        for (int k4 = 0; k4 < 32; ++k4) {
            f4 a[4], w[4];
            #pragma unroll
            for (int d = 0; d < 4; ++d) {
                int rm = ty + 16 * d;
                a[d] = Y4[rm][k4 ^ (rm & 31)];
                int rc = tx + 16 * d;
                w[d] = W4[rc][k4 ^ (rc & 31)];
            }
            #pragma unroll
            for (int di = 0; di < 4; ++di)
                #pragma unroll
                for (int dj = 0; dj < 4; ++dj)
                    acc[di][dj] += a[di].x * w[dj].x + a[di].y * w[dj].y +
                                   a[di].z * w[dj].z + a[di].w * w[dj].w;
        }
        #pragma unroll
        for (int di = 0; di < 4; ++di)
            #pragma unroll
            for (int dj = 0; dj < 4; ++dj) {
                int m = ty + 16 * di, co = half * 64 + tx + 16 * dj;
                float v = acc[di][dj];
                yb[(size_t)m * C_ + co] = v / (1.f + __expf(-v));
            }
    }
}

// ----------------------------------------------------------------
extern "C" void kernel_launch(void* const* d_in, const int* in_sizes, int n_in,
                              void* d_out, int out_size, void* d_ws, size_t ws_size,
                              hipStream_t stream) {
    (void)in_sizes; (void)n_in; (void)out_size; (void)ws_size;
    const float* x = (const float*)d_in[0];
    const float* W = (const float*)d_in[1];
    float* out = (float*)d_out;

    char* ws = (char*)d_ws;
    size_t o = 0;
    auto alloc = [&](size_t n) { size_t r = o; o += (n + 255) & ~(size_t)255; return r; };
    double* off_part = (double*)(ws + alloc((size_t)B_ * 256 * 8));      // 32KB
    float*  invh     = (float*) (ws + alloc(B_ * 4));
    float*  sqv      = (float*) (ws + alloc((size_t)B_ * M_ * 4));       // 128KB
    float*  rho      = (float*) (ws + alloc((size_t)B_ * M_ * 4));       // 128KB
    int*    perm     = (int*)   (ws + alloc((size_t)B_ * M_ * 4));       // 128KB
    float*  g        = (float*) (ws + alloc(M_ * 4));
    float*  dvs      = (float*) (ws + alloc(M_ * 4));
    double* chunkU   = (double*)(ws + alloc((size_t)B_ * 16 * C_ * 8));  // 256KB
    double* chunkGU  = (double*)(ws + alloc((size_t)B_ * 16 * C_ * 8));  // 256KB
    // rho_part (4MB) lives in the front of d_out; consumed before y is written.
    float* rho_part = out;

    sq_kernel<<<(B_ * M_) / 4, 256, 0, stream>>>(x, sqv);
    gram_mfma<0><<<dim3(16, 16, B_), 256, 0, stream>>>(x, sqv, nullptr, off_part, nullptr);
    offreduce_kernel<<<B_, 256, 0, stream>>>(off_part, invh);
    gram_mfma<1><<<dim3(16, 16, B_), 256, 0, stream>>>(x, sqv, invh, nullptr, rho_part);
    rho_reduce<<<(B_ * M_) / 256, 256, 0, stream>>>(rho_part, rho);
    rank_kernel<<<dim3(M_ / 256, B_), 256, 0, stream>>>(rho, perm);
    g_kernel<<<1, 256, 0, stream>>>(g, dvs);
    scan_chunk<<<dim3(B_, 16), 128, 0, stream>>>(x, perm, g, dvs, chunkU, chunkGU);
    scan_final<<<dim3(B_, 16), 128, 0, stream>>>(x, perm, g, dvs, chunkU, chunkGU, out);
    linear_silu<<<dim3(M_ / 64, B_), 256, 0, stream>>>(out, W);
}

// Round 3
// 229.608 us; speedup vs baseline: 3.3166x; 1.6223x over previous
//
#include <hip/hip_runtime.h>
#include <math.h>

#define B_ 16
#define M_ 2048
#define C_ 128

using f4 = float4;
typedef __attribute__((ext_vector_type(8))) short bf16x8;
typedef __attribute__((ext_vector_type(16))) float f32x16;

// round-to-nearest-even f32 -> bf16 bits
__device__ inline unsigned short bfr(float f) {
    unsigned int u = __float_as_uint(f);
    return (unsigned short)((u + 0x7FFFu + ((u >> 16) & 1u)) >> 16);
}

// ---------------------------------------------------------------- x -> xhi, xlo (bf16), sq
// block: 256 thr = 4 waves; wave handles 2 rows (l5 picks row, l31 picks f4 chunk)
__global__ __launch_bounds__(256) void prep_kernel(const float* __restrict__ x,
                                                   uint2* __restrict__ xhi,
                                                   uint2* __restrict__ xlo,
                                                   float* __restrict__ sq) {
    int wid = threadIdx.x >> 6, lane = threadIdx.x & 63;
    int l31 = lane & 31, l5 = lane >> 5;
    int row = blockIdx.x * 8 + wid * 2 + l5;
    f4 v = ((const f4*)(x + (size_t)row * C_))[l31];
    unsigned short h0 = bfr(v.x), h1 = bfr(v.y), h2 = bfr(v.z), h3 = bfr(v.w);
    float r0 = v.x - __uint_as_float((unsigned)h0 << 16);
    float r1 = v.y - __uint_as_float((unsigned)h1 << 16);
    float r2 = v.z - __uint_as_float((unsigned)h2 << 16);
    float r3 = v.w - __uint_as_float((unsigned)h3 << 16);
    unsigned short l0 = bfr(r0), l1 = bfr(r1), l2 = bfr(r2), l3 = bfr(r3);
    uint2 hp, lp;
    hp.x = (unsigned)h0 | ((unsigned)h1 << 16);
    hp.y = (unsigned)h2 | ((unsigned)h3 << 16);
    lp.x = (unsigned)l0 | ((unsigned)l1 << 16);
    lp.y = (unsigned)l2 | ((unsigned)l3 << 16);
    xhi[(size_t)row * 32 + l31] = hp;          // 256B per row
    xlo[(size_t)row * 32 + l31] = lp;
    float dot = v.x * v.x + v.y * v.y + v.z * v.z + v.w * v.w;
    #pragma unroll
    for (int m = 1; m < 32; m <<= 1) dot += __shfl_xor(dot, m);
    if (l31 == 0) sq[row] = dot;
}

// ---------------------------------------------------------------- persistent-panel MFMA Gram
// Block = (i-panel, batch). A panel (128 rows) -> registers once; loop over all 16 j-panels
// with B double-buffered in LDS via async global_load_lds (pre-swizzled source, linear dest).
// MODE 0: hi*hi -> off-diag dist sum -> off_part[b][ip]
// MODE 1: hi*hi+hi*lo+lo*hi -> rho[b][point] written directly.
template <int MODE>
__global__ __launch_bounds__(512, 2) void gram_mfma(
    const char* __restrict__ xhi, const char* __restrict__ xlo,
    const float* __restrict__ sq, const float* __restrict__ invh,
    double* __restrict__ off_part, float* __restrict__ rho) {
    constexpr int TB = (MODE == 1) ? 65536 : 32768;   // per-buffer bytes (hi[+lo])
    __shared__ __align__(16) char lds[2 * TB];
    int tid = threadIdx.x, lane = tid & 63, wid = tid >> 6;
    int l31 = lane & 31, l5 = lane >> 5;
    int wr = wid >> 2, wc = wid & 3;                  // wave tile: rows wr*64(+64), cols wc*32(+32)
    int ip = blockIdx.x, b = blockIdx.y;
    const char* hbase = xhi + (size_t)b * M_ * 256;
    const char* lbase = xlo + (size_t)b * M_ * 256;
    char* buf0 = lds;
    char* buf1 = lds + TB;

    // stage one 32KB tile (128 rows x 16 swizzled 16B slots), linear LDS dest
    auto stageT = [&](const char* src, char* dst) {
        #pragma unroll
        for (int q = 0; q < 4; ++q) {
            int inst = wid * 4 + q;
            int row  = inst * 4 + (lane >> 4);
            int ch   = (lane & 15) ^ (row & 15);
            __builtin_amdgcn_global_load_lds(
                (const __attribute__((address_space(1))) unsigned int*)(src + row * 256 + ch * 16),
                (__attribute__((address_space(3))) unsigned int*)(dst + inst * 1024),
                16, 0, 0);
        }
    };

    // prologue: A panel -> buf1 -> registers
    stageT(hbase + (size_t)ip * 32768, buf1);
    if (MODE == 1) stageT(lbase + (size_t)ip * 32768, buf1 + 32768);
    __syncthreads();
    stageT(hbase, buf0);                              // B[0] (overlaps A frag reads)
    if (MODE == 1) stageT(lbase, buf0 + 32768);
    bf16x8 ahi[2][8], alo[2][8];
    #pragma unroll
    for (int fi = 0; fi < 2; ++fi)
        #pragma unroll
        for (int ks = 0; ks < 8; ++ks) {
            int row = wr * 64 + fi * 32 + l31;
            int ch  = ((ks << 1) | l5) ^ (row & 15);
            ahi[fi][ks] = *(const bf16x8*)(buf1 + row * 256 + ch * 16);
            if (MODE == 1)
                alo[fi][ks] = *(const bf16x8*)(buf1 + 32768 + row * 256 + ch * 16);
        }
    __syncthreads();

    float svh = 0.f;
    if (MODE == 1) svh = invh[b] * 1.4426950408889634f;   // s * log2(e)
    float c2 = 2.f * svh;
    f32x16 rs0 = {}, rs1 = {};                        // MODE1 row-sum accumulators
    float part = 0.f;                                 // MODE0
    float si[2][16];
    if (MODE == 0) {
        #pragma unroll
        for (int fi = 0; fi < 2; ++fi)
            #pragma unroll
            for (int rg = 0; rg < 16; ++rg) {
                int rl = (rg & 3) + ((rg >> 2) << 3) + (l5 << 2);
                si[fi][rg] = sq[b * M_ + ip * 128 + wr * 64 + fi * 32 + rl];
            }
    }

    for (int s = 0; s < 16; ++s) {
        char* cur = (s & 1) ? buf1 : buf0;
        char* nxt = (s & 1) ? buf0 : buf1;
        if (s < 15) {                                 // async prefetch next B panel
            stageT(hbase + (size_t)(s + 1) * 32768, nxt);
            if (MODE == 1) stageT(lbase + (size_t)(s + 1) * 32768, nxt + 32768);
        }
        float sqj = sq[b * M_ + s * 128 + wc * 32 + l31];
        f32x16 acc0 = {}, acc1 = {};
        #pragma unroll
        for (int ks = 0; ks < 8; ++ks) {
            int brow = wc * 32 + l31;
            int ch   = ((ks << 1) | l5) ^ (brow & 15);
            bf16x8 bh = *(const bf16x8*)(cur + brow * 256 + ch * 16);
            acc0 = __builtin_amdgcn_mfma_f32_32x32x16_bf16(ahi[0][ks], bh, acc0, 0, 0, 0);
            acc1 = __builtin_amdgcn_mfma_f32_32x32x16_bf16(ahi[1][ks], bh, acc1, 0, 0, 0);
            if (MODE == 1) {
                bf16x8 bl = *(const bf16x8*)(cur + 32768 + brow * 256 + ch * 16);
                acc0 = __builtin_amdgcn_mfma_f32_32x32x16_bf16(alo[0][ks], bh, acc0, 0, 0, 0);
                acc1 = __builtin_amdgcn_mfma_f32_32x32x16_bf16(alo[1][ks], bh, acc1, 0, 0, 0);
                acc0 = __builtin_amdgcn_mfma_f32_32x32x16_bf16(ahi[0][ks], bl, acc0, 0, 0, 0);
                acc1 = __builtin_amdgcn_mfma_f32_32x32x16_bf16(ahi[1][ks], bl, acc1, 0, 0, 0);
            }
        }
        if (MODE == 1) {
            float m = -sqj * svh;
            #pragma unroll
            for (int rg = 0; rg < 16; ++rg) {
                rs0[rg] += exp2f(fmaf(acc0[rg], c2, m));
                rs1[rg] += exp2f(fmaf(acc1[rg], c2, m));
            }
        } else {
            bool dg = (s == ip);
            int colt = wc * 32 + l31;
            #pragma unroll
            for (int rg = 0; rg < 16; ++rg) {
                int rl = (rg & 3) + ((rg >> 2) << 3) + (l5 << 2);
                float d0 = si[0][rg] + sqj - 2.f * acc0[rg];
                float d1 = si[1][rg] + sqj - 2.f * acc1[rg];
                float s0 = sqrtf(fmaxf(d0, 1e-12f));
                float s1 = sqrtf(fmaxf(d1, 1e-12f));
                if (dg && (wr * 64 + rl) == colt) s0 = 0.f;
                if (dg && (wr * 64 + 32 + rl) == colt) s1 = 0.f;
                part += s0 + s1;
            }
        }
        __syncthreads();                              // drains prefetch + LDS reads
    }

    if (MODE == 1) {
        // reduce over the 32 cols (l31) per (rg, l5); rows stay per-lane
        #pragma unroll
        for (int rg = 0; rg < 16; ++rg) {
            float v0 = rs0[rg], v1 = rs1[rg];
            #pragma unroll
            for (int m = 1; m < 32; m <<= 1) { v0 += __shfl_xor(v0, m); v1 += __shfl_xor(v1, m); }
            rs0[rg] = v0; rs1[rg] = v1;
        }
        __syncthreads();
        float* scr = (float*)lds;                     // [wc][128]
        if (l31 == 0) {
            #pragma unroll
            for (int rg = 0; rg < 16; ++rg) {
                int r0 = wr * 64 + (rg & 3) + ((rg >> 2) << 3) + (l5 << 2);
                scr[wc * 128 + r0]      = rs0[rg];
                scr[wc * 128 + r0 + 32] = rs1[rg];
            }
        }
        __syncthreads();
        if (tid < 128) {
            int pt = b * M_ + ip * 128 + tid;
            float tot = scr[tid] + scr[128 + tid] + scr[256 + tid] + scr[384 + tid];
            rho[pt] = exp2f(-sq[pt] * svh) * tot;
        }
    } else {
        #pragma unroll
        for (int m = 1; m < 64; m <<= 1) part += __shfl_xor(part, m);
        __syncthreads();
        double* dscr = (double*)lds;
        if (lane == 0) dscr[wid] = (double)part;
        __syncthreads();
        if (tid == 0) {
            double t = 0.0;
            #pragma unroll
            for (int w = 0; w < 8; ++w) t += dscr[w];
            off_part[b * 16 + ip] = t;
        }
    }
}

// ---------------------------------------------------------------- h -> 1/(2h^2) per batch
__global__ __launch_bounds__(256) void offreduce_kernel(const double* __restrict__ op,
                                                        float* __restrict__ invh) {
    int tid = threadIdx.x, b = tid >> 4, k = tid & 15;
    double v = op[b * 16 + k];
    #pragma unroll
    for (int m = 1; m < 16; m <<= 1) v += __shfl_xor(v, m);
    if (k == 0) {
        double h = v / ((double)M_ * (double)(M_ - 1));
        h = h > 1e-6 ? h : 1e-6;
        invh[b] = (float)(1.0 / (2.0 * h * h));
    }
}

// ---------------------------------------------------------------- rank + scatter permutation
__global__ __launch_bounds__(256) void rank_kernel(const float* __restrict__ rho,
                                                   int* __restrict__ perm) {
    int b = blockIdx.y;
    int i = blockIdx.x * 256 + threadIdx.x;
    __shared__ float r[M_];
    const float* rb = rho + b * M_;
    for (int t = threadIdx.x; t < M_; t += 256) r[t] = rb[t];
    __syncthreads();
    float rv = r[i];
    int cnt = 0;
    for (int j = 0; j < M_; ++j) {
        float o = r[j];
        cnt += (o < rv || (o == rv && j < i)) ? 1 : 0;
    }
    perm[b * M_ + cnt] = i;
}

// ---------------------------------------------------------------- g_t, dvs_t tables
__global__ __launch_bounds__(256) void g_kernel(float* __restrict__ g, float* __restrict__ dvs) {
    int tid = threadIdx.x;
    __shared__ double w[256];
    double loc = 0.0;
    #pragma unroll
    for (int q = 0; q < 8; ++q) loc += 1.0 / (double)(M_ - (tid * 8 + q));
    w[tid] = loc; __syncthreads();
    for (int o = 1; o < 256; o <<= 1) {
        double v = (tid >= o) ? w[tid - o] : 0.0;
        __syncthreads();
        w[tid] += v;
        __syncthreads();
    }
    double acc = (tid > 0) ? w[tid - 1] : 0.0;
    #pragma unroll
    for (int q = 0; q < 8; ++q) {
        int t = tid * 8 + q;
        acc += 1.0 / (double)(M_ - t);
        g[t]   = (float)acc;
        dvs[t] = (float)(1.0 / sqrt((double)(t + 1)));
    }
}

// ---------------------------------------------------------------- per-chunk partial sums
__global__ __launch_bounds__(128) void scan_chunk(
    const float* __restrict__ x, const int* __restrict__ perm,
    const float* __restrict__ g, const float* __restrict__ dvs,
    double* __restrict__ chunkU, double* __restrict__ chunkGU) {
    int b = blockIdx.x, ch = blockIdx.y, c = threadIdx.x;
    __shared__ int   pidx[128];
    __shared__ float gl[128], dl[128];
    int t0 = ch * 128;
    pidx[c] = perm[b * M_ + t0 + c];
    gl[c]   = g[t0 + c];
    dl[c]   = dvs[t0 + c];
    __syncthreads();
    const float* xb = x + (size_t)b * M_ * C_;
    double sU = 0.0, sGU = 0.0;
    for (int tt = 0; tt < 128; ++tt) {
        double u = (double)xb[(size_t)pidx[tt] * C_ + c] * (double)dl[tt];
        sU  += u;
        sGU += (double)gl[tt] * u;
    }
    chunkU [(size_t)(b * 16 + ch) * 128 + c] = sU;
    chunkGU[(size_t)(b * 16 + ch) * 128 + c] = sGU;
}

// ---------------------------------------------------------------- y via two prefix scans
__global__ __launch_bounds__(128) void scan_final(
    const float* __restrict__ x, const int* __restrict__ perm,
    const float* __restrict__ g, const float* __restrict__ dvs,
    const double* __restrict__ chunkU, const double* __restrict__ chunkGU,
    float* __restrict__ y) {
    int b = blockIdx.x, ch = blockIdx.y, c = threadIdx.x;
    __shared__ int   pidx[128];
    __shared__ float gl[128], dl[128];
    int t0 = ch * 128;
    pidx[c] = perm[b * M_ + t0 + c];
    gl[c]   = g[t0 + c];
    dl[c]   = dvs[t0 + c];
    __syncthreads();
    double Utot = 0.0, runU = 0.0, runG = 0.0;
    for (int q = 0; q < 16; ++q) {
        double cu = chunkU[(size_t)(b * 16 + q) * 128 + c];
        Utot += cu;
        if (q < ch) { runU += cu; runG += chunkGU[(size_t)(b * 16 + q) * 128 + c]; }
    }
    const float* xb = x + (size_t)b * M_ * C_;
    float*       yb = y + (size_t)b * M_ * C_;
    for (int tt = 0; tt < 128; ++tt) {
        int idx = pidx[tt];
        double u  = (double)xb[(size_t)idx * C_ + c] * (double)dl[tt];
        double yv = (double)dl[tt] * ((double)gl[tt] * (Utot - runU) + runG);
        yb[(size_t)idx * C_ + c] = (float)yv;
        runU += u;
        runG += (double)gl[tt] * u;
    }
}

// ---------------------------------------------------------------- out = SiLU(y @ W^T), in-place
__global__ __launch_bounds__(256, 2) void linear_silu(float* __restrict__ y,
                                                      const float* __restrict__ W) {
    int b = blockIdx.y, m0 = blockIdx.x * 64;
    __shared__ f4 Y4[64][32];
    __shared__ f4 W4[64][32];
    float* yb = y + ((size_t)b * M_ + m0) * C_;
    int tid = threadIdx.x;
    for (int s = tid; s < 64 * 32; s += 256) {
        int row = s >> 5, c4 = s & 31;
        Y4[row][c4 ^ (row & 31)] = ((const f4*)(yb + (size_t)row * C_))[c4];
    }
    int tx = tid & 15, ty = tid >> 4;
    for (int half = 0; half < 2; ++half) {
        __syncthreads();
        for (int s = tid; s < 64 * 32; s += 256) {
            int row = s >> 5, c4 = s & 31;
            W4[row][c4 ^ (row & 31)] = ((const f4*)(W + (size_t)(half * 64 + row) * C_))[c4];
        }
        __syncthreads();
        float acc[4][4] = {};
        #pragma unroll 4
        for (int k4 = 0; k4 < 32; ++k4) {
            f4 a[4], w[4];
            #pragma unroll
            for (int d = 0; d < 4; ++d) {
                int rm = ty + 16 * d;
                a[d] = Y4[rm][k4 ^ (rm & 31)];
                int rc = tx + 16 * d;
                w[d] = W4[rc][k4 ^ (rc & 31)];
            }
            #pragma unroll
            for (int di = 0; di < 4; ++di)
                #pragma unroll
                for (int dj = 0; dj < 4; ++dj)
                    acc[di][dj] += a[di].x * w[dj].x + a[di].y * w[dj].y +
                                   a[di].z * w[dj].z + a[di].w * w[dj].w;
        }
        #pragma unroll
        for (int di = 0; di < 4; ++di)
            #pragma unroll
            for (int dj = 0; dj < 4; ++dj) {
                int m = ty + 16 * di, co = half * 64 + tx + 16 * dj;
                float v = acc[di][dj];
                yb[(size_t)m * C_ + co] = v / (1.f + __expf(-v));
            }
    }
}

// ----------------------------------------------------------------
extern "C" void kernel_launch(void* const* d_in, const int* in_sizes, int n_in,
                              void* d_out, int out_size, void* d_ws, size_t ws_size,
                              hipStream_t stream) {
    (void)in_sizes; (void)n_in; (void)out_size; (void)ws_size;
    const float* x = (const float*)d_in[0];
    const float* W = (const float*)d_in[1];
    float* out = (float*)d_out;

    char* ws = (char*)d_ws;
    size_t o = 0;
    auto alloc = [&](size_t n) { size_t r = o; o += (n + 255) & ~(size_t)255; return r; };
    double* off_part = (double*)(ws + alloc((size_t)B_ * 16 * 8));
    float*  invh     = (float*) (ws + alloc(B_ * 4));
    float*  sqv      = (float*) (ws + alloc((size_t)B_ * M_ * 4));       // 128KB
    float*  rho      = (float*) (ws + alloc((size_t)B_ * M_ * 4));       // 128KB
    int*    perm     = (int*)   (ws + alloc((size_t)B_ * M_ * 4));       // 128KB
    float*  g        = (float*) (ws + alloc(M_ * 4));
    float*  dvs      = (float*) (ws + alloc(M_ * 4));
    double* chunkU   = (double*)(ws + alloc((size_t)B_ * 16 * C_ * 8));  // 256KB
    double* chunkGU  = (double*)(ws + alloc((size_t)B_ * 16 * C_ * 8));  // 256KB
    // xhi/xlo bf16 (8MB each) live in d_out; consumed by grams before y is written.
    char* xhi = (char*)d_out;
    char* xlo = xhi + (size_t)B_ * M_ * 256;

    prep_kernel<<<(B_ * M_) / 8, 256, 0, stream>>>(x, (uint2*)xhi, (uint2*)xlo, sqv);
    gram_mfma<0><<<dim3(16, B_), 512, 0, stream>>>(xhi, xlo, sqv, nullptr, off_part, nullptr);
    offreduce_kernel<<<1, 256, 0, stream>>>(off_part, invh);
    gram_mfma<1><<<dim3(16, B_), 512, 0, stream>>>(xhi, xlo, sqv, invh, nullptr, rho);
    rank_kernel<<<dim3(M_ / 256, B_), 256, 0, stream>>>(rho, perm);
    g_kernel<<<1, 256, 0, stream>>>(g, dvs);
    scan_chunk<<<dim3(B_, 16), 128, 0, stream>>>(x, perm, g, dvs, chunkU, chunkGU);
    scan_final<<<dim3(B_, 16), 128, 0, stream>>>(x, perm, g, dvs, chunkU, chunkGU, out);
    linear_silu<<<dim3(M_ / 64, B_), 256, 0, stream>>>(out, W);
}

// Round 4
// 227.750 us; speedup vs baseline: 3.3437x; 1.0082x over previous
//
#include <hip/hip_runtime.h>
#include <math.h>

#define B_ 16
#define M_ 2048
#define C_ 128

using f4 = float4;
typedef __attribute__((ext_vector_type(8))) short bf16x8;
typedef __attribute__((ext_vector_type(16))) float f32x16;

// round-to-nearest-even f32 -> bf16 bits
__device__ inline unsigned short bfr(float f) {
    unsigned int u = __float_as_uint(f);
    return (unsigned short)((u + 0x7FFFu + ((u >> 16) & 1u)) >> 16);
}

// ---------------------------------------------------------------- x -> xhi, xlo (bf16), sq
__global__ __launch_bounds__(256) void prep_kernel(const float* __restrict__ x,
                                                   uint2* __restrict__ xhi,
                                                   uint2* __restrict__ xlo,
                                                   float* __restrict__ sq) {
    int wid = threadIdx.x >> 6, lane = threadIdx.x & 63;
    int l31 = lane & 31, l5 = lane >> 5;
    int row = blockIdx.x * 8 + wid * 2 + l5;
    f4 v = ((const f4*)(x + (size_t)row * C_))[l31];
    unsigned short h0 = bfr(v.x), h1 = bfr(v.y), h2 = bfr(v.z), h3 = bfr(v.w);
    float r0 = v.x - __uint_as_float((unsigned)h0 << 16);
    float r1 = v.y - __uint_as_float((unsigned)h1 << 16);
    float r2 = v.z - __uint_as_float((unsigned)h2 << 16);
    float r3 = v.w - __uint_as_float((unsigned)h3 << 16);
    unsigned short l0 = bfr(r0), l1 = bfr(r1), l2 = bfr(r2), l3 = bfr(r3);
    uint2 hp, lp;
    hp.x = (unsigned)h0 | ((unsigned)h1 << 16);
    hp.y = (unsigned)h2 | ((unsigned)h3 << 16);
    lp.x = (unsigned)l0 | ((unsigned)l1 << 16);
    lp.y = (unsigned)l2 | ((unsigned)l3 << 16);
    xhi[(size_t)row * 32 + l31] = hp;          // 256B per row
    xlo[(size_t)row * 32 + l31] = lp;
    float dot = v.x * v.x + v.y * v.y + v.z * v.z + v.w * v.w;
    #pragma unroll
    for (int m = 1; m < 32; m <<= 1) dot += __shfl_xor(dot, m);
    if (l31 == 0) sq[row] = dot;
}

// ---------------------------------------------------------------- persistent-panel MFMA Gram
// 4-phase pipelined K-loop, 1 raw barrier/step, counted prefetch (T3+T4), setprio (T5),
// XCD-swizzled grid (T1). MODE 0: hi*hi -> off-diag dist sum. MODE 1: 3-product -> rho direct.
template <int MODE>
__global__ __launch_bounds__(512, 2) void gram_mfma(
    const char* __restrict__ xhi, const char* __restrict__ xlo,
    const float* __restrict__ sq, const float* __restrict__ invh,
    double* __restrict__ off_part, float* __restrict__ rho) {
    constexpr int TB = (MODE == 1) ? 65536 : 32768;   // per-buffer bytes (hi[+lo])
    __shared__ __align__(16) char lds[2 * TB];
    int tid = threadIdx.x, lane = tid & 63, wid = tid >> 6;
    int l31 = lane & 31, l5 = lane >> 5;
    int wr = wid >> 2, wc = wid & 3;                  // wave tile: rows wr*64(+64), cols wc*32
    int bid = blockIdx.x;
    int swz = (bid & 7) * 32 + (bid >> 3);            // bijective XCD swizzle (256 = 8*32)
    int b = swz >> 4, ip = swz & 15;
    const char* hbase = xhi + (size_t)b * M_ * 256;
    const char* lbase = xlo + (size_t)b * M_ * 256;
    char* buf0 = lds;
    char* buf1 = lds + TB;

    // one 1KB global_load_lds slice (inst q of 4 per wave) of a 32KB panel tile
    auto stage1 = [&](const char* src, char* dst, int q) {
        int inst = wid * 4 + q;
        int row  = inst * 4 + (lane >> 4);
        int ch   = (lane & 15) ^ (row & 15);
        __builtin_amdgcn_global_load_lds(
            (const __attribute__((address_space(1))) unsigned int*)(src + row * 256 + ch * 16),
            (__attribute__((address_space(3))) unsigned int*)(dst + inst * 1024),
            16, 0, 0);
    };
    auto stageAll = [&](const char* src, char* dst) {
        #pragma unroll
        for (int q = 0; q < 4; ++q) stage1(src, dst, q);
    };

    // prologue: A panel -> buf1 -> registers; then B0 -> buf0
    stageAll(hbase + (size_t)ip * 32768, buf1);
    if (MODE == 1) stageAll(lbase + (size_t)ip * 32768, buf1 + 32768);
    __syncthreads();
    bf16x8 ahi[2][8], alo[2][8];
    #pragma unroll
    for (int fi = 0; fi < 2; ++fi)
        #pragma unroll
        for (int ks = 0; ks < 8; ++ks) {
            int row = wr * 64 + fi * 32 + l31;
            int ch  = ((ks << 1) | l5) ^ (row & 15);
            ahi[fi][ks] = *(const bf16x8*)(buf1 + row * 256 + ch * 16);
            if (MODE == 1)
                alo[fi][ks] = *(const bf16x8*)(buf1 + 32768 + row * 256 + ch * 16);
        }
    // A-frag ds_reads MUST complete before panel-1 DMA overwrites buf1 (issued after
    // the first in-loop barrier) -> drain lgkm before reaching that barrier.
    asm volatile("s_waitcnt lgkmcnt(0)" ::: "memory");
    __builtin_amdgcn_sched_barrier(0);
    stageAll(hbase, buf0);
    if (MODE == 1) stageAll(lbase, buf0 + 32768);

    float svh = 0.f;
    if (MODE == 1) svh = invh[b] * 1.4426950408889634f;   // s * log2(e)
    float c2 = 2.f * svh;
    f32x16 rs0 = {}, rs1 = {};
    float part = 0.f;
    float si[2][16];
    if (MODE == 0) {
        #pragma unroll
        for (int fi = 0; fi < 2; ++fi)
            #pragma unroll
            for (int rg = 0; rg < 16; ++rg) {
                int rl = (rg & 3) + ((rg >> 2) << 3) + (l5 << 2);
                si[fi][rg] = sq[b * M_ + ip * 128 + wr * 64 + fi * 32 + rl];
            }
    }

    #pragma unroll 1
    for (int s = 0; s < 16; ++s) {
        char* cur = (s & 1) ? buf1 : buf0;
        char* nxt = (s & 1) ? buf0 : buf1;
        const char* hs = hbase + (size_t)(s + 1) * 32768;
        const char* ls = lbase + (size_t)(s + 1) * 32768;
        const bool pf = (s < 15);
        // step boundary: drain this wave's loads for panel s (the only vmem outstanding),
        // then barrier => panel s resident for ALL waves, and all waves done reading
        // buf[nxt] (their step s-1 compute) => safe to DMA panel s+1 into nxt after this.
        asm volatile("s_waitcnt vmcnt(0)" ::: "memory");
        __builtin_amdgcn_s_barrier();
        float sqj = sq[b * M_ + s * 128 + wc * 32 + l31];
        f32x16 acc0 = {}, acc1 = {};
        #pragma unroll
        for (int p = 0; p < 4; ++p) {                 // 2 k-slices per phase
            if (pf) {
                stage1(hs, nxt, p);
                if (MODE == 1) stage1(ls, nxt + 32768, p);
            }
            int brow = wc * 32 + l31;
            int ks0 = 2 * p;
            int ch0 = ((ks0 << 1) | l5) ^ (brow & 15);
            int ch1 = (((ks0 + 1) << 1) | l5) ^ (brow & 15);
            bf16x8 bh0 = *(const bf16x8*)(cur + brow * 256 + ch0 * 16);
            bf16x8 bh1 = *(const bf16x8*)(cur + brow * 256 + ch1 * 16);
            bf16x8 bl0, bl1;
            if (MODE == 1) {
                bl0 = *(const bf16x8*)(cur + 32768 + brow * 256 + ch0 * 16);
                bl1 = *(const bf16x8*)(cur + 32768 + brow * 256 + ch1 * 16);
            }
            __builtin_amdgcn_s_setprio(1);
            acc0 = __builtin_amdgcn_mfma_f32_32x32x16_bf16(ahi[0][ks0], bh0, acc0, 0, 0, 0);
            acc1 = __builtin_amdgcn_mfma_f32_32x32x16_bf16(ahi[1][ks0], bh0, acc1, 0, 0, 0);
            acc0 = __builtin_amdgcn_mfma_f32_32x32x16_bf16(ahi[0][ks0 + 1], bh1, acc0, 0, 0, 0);
            acc1 = __builtin_amdgcn_mfma_f32_32x32x16_bf16(ahi[1][ks0 + 1], bh1, acc1, 0, 0, 0);
            if (MODE == 1) {
                acc0 = __builtin_amdgcn_mfma_f32_32x32x16_bf16(alo[0][ks0], bh0, acc0, 0, 0, 0);
                acc1 = __builtin_amdgcn_mfma_f32_32x32x16_bf16(alo[1][ks0], bh0, acc1, 0, 0, 0);
                acc0 = __builtin_amdgcn_mfma_f32_32x32x16_bf16(ahi[0][ks0], bl0, acc0, 0, 0, 0);
                acc1 = __builtin_amdgcn_mfma_f32_32x32x16_bf16(ahi[1][ks0], bl0, acc1, 0, 0, 0);
                acc0 = __builtin_amdgcn_mfma_f32_32x32x16_bf16(alo[0][ks0 + 1], bh1, acc0, 0, 0, 0);
                acc1 = __builtin_amdgcn_mfma_f32_32x32x16_bf16(alo[1][ks0 + 1], bh1, acc1, 0, 0, 0);
                acc0 = __builtin_amdgcn_mfma_f32_32x32x16_bf16(ahi[0][ks0 + 1], bl1, acc0, 0, 0, 0);
                acc1 = __builtin_amdgcn_mfma_f32_32x32x16_bf16(ahi[1][ks0 + 1], bl1, acc1, 0, 0, 0);
            }
            __builtin_amdgcn_s_setprio(0);
        }
        if (MODE == 1) {
            float m = -sqj * svh;
            #pragma unroll
            for (int rg = 0; rg < 16; ++rg) {
                rs0[rg] += exp2f(fmaf(acc0[rg], c2, m));
                rs1[rg] += exp2f(fmaf(acc1[rg], c2, m));
            }
        } else {
            bool dg = (s == ip);
            int colt = wc * 32 + l31;
            #pragma unroll
            for (int rg = 0; rg < 16; ++rg) {
                int rl = (rg & 3) + ((rg >> 2) << 3) + (l5 << 2);
                float d0 = si[0][rg] + sqj - 2.f * acc0[rg];
                float d1 = si[1][rg] + sqj - 2.f * acc1[rg];
                float s0 = sqrtf(fmaxf(d0, 1e-12f));
                float s1 = sqrtf(fmaxf(d1, 1e-12f));
                if (dg && (wr * 64 + rl) == colt) s0 = 0.f;
                if (dg && (wr * 64 + 32 + rl) == colt) s1 = 0.f;
                part += s0 + s1;
            }
        }
    }

    if (MODE == 1) {
        #pragma unroll
        for (int rg = 0; rg < 16; ++rg) {
            float v0 = rs0[rg], v1 = rs1[rg];
            #pragma unroll
            for (int m = 1; m < 32; m <<= 1) { v0 += __shfl_xor(v0, m); v1 += __shfl_xor(v1, m); }
            rs0[rg] = v0; rs1[rg] = v1;
        }
        __syncthreads();
        float* scr = (float*)lds;                     // [wc][128]
        if (l31 == 0) {
            #pragma unroll
            for (int rg = 0; rg < 16; ++rg) {
                int r0 = wr * 64 + (rg & 3) + ((rg >> 2) << 3) + (l5 << 2);
                scr[wc * 128 + r0]      = rs0[rg];
                scr[wc * 128 + r0 + 32] = rs1[rg];
            }
        }
        __syncthreads();
        if (tid < 128) {
            int pt = b * M_ + ip * 128 + tid;
            float tot = scr[tid] + scr[128 + tid] + scr[256 + tid] + scr[384 + tid];
            rho[pt] = exp2f(-sq[pt] * svh) * tot;
        }
    } else {
        #pragma unroll
        for (int m = 1; m < 64; m <<= 1) part += __shfl_xor(part, m);
        __syncthreads();
        double* dscr = (double*)lds;
        if (lane == 0) dscr[wid] = (double)part;
        __syncthreads();
        if (tid == 0) {
            double t = 0.0;
            #pragma unroll
            for (int w = 0; w < 8; ++w) t += dscr[w];
            off_part[b * 16 + ip] = t;
        }
    }
}

// ---------------------------------------------------------------- fused: invh (block 0) + g/dvs (block 1)
__global__ __launch_bounds__(256) void small_kernel(const double* __restrict__ op,
                                                    float* __restrict__ invh,
                                                    float* __restrict__ g,
                                                    float* __restrict__ dvs) {
    int tid = threadIdx.x;
    if (blockIdx.x == 0) {
        int b = tid >> 4, k = tid & 15;
        double v = op[b * 16 + k];
        #pragma unroll
        for (int m = 1; m < 16; m <<= 1) v += __shfl_xor(v, m);
        if (k == 0) {
            double h = v / ((double)M_ * (double)(M_ - 1));
            h = h > 1e-6 ? h : 1e-6;
            invh[b] = (float)(1.0 / (2.0 * h * h));
        }
    } else {
        __shared__ double w[256];
        double loc = 0.0;
        #pragma unroll
        for (int q = 0; q < 8; ++q) loc += 1.0 / (double)(M_ - (tid * 8 + q));
        w[tid] = loc; __syncthreads();
        for (int o = 1; o < 256; o <<= 1) {
            double v = (tid >= o) ? w[tid - o] : 0.0;
            __syncthreads();
            w[tid] += v;
            __syncthreads();
        }
        double acc = (tid > 0) ? w[tid - 1] : 0.0;
        #pragma unroll
        for (int q = 0; q < 8; ++q) {
            int t = tid * 8 + q;
            acc += 1.0 / (double)(M_ - t);
            g[t]   = (float)acc;
            dvs[t] = (float)(1.0 / sqrt((double)(t + 1)));
        }
    }
}

// ---------------------------------------------------------------- rank + scatter permutation
__global__ __launch_bounds__(128) void rank_kernel(const float* __restrict__ rho,
                                                   int* __restrict__ perm) {
    int b = blockIdx.y;
    int i = blockIdx.x * 128 + threadIdx.x;
    __shared__ float r[M_];
    const float* rb = rho + b * M_;
    for (int t = threadIdx.x; t < M_; t += 128) r[t] = rb[t];
    __syncthreads();
    float rv = r[i];
    int cnt = 0;
    #pragma unroll 4
    for (int j = 0; j < M_; ++j) {
        float o = r[j];
        cnt += (o < rv || (o == rv && j < i)) ? 1 : 0;
    }
    perm[b * M_ + cnt] = i;
}

// ---------------------------------------------------------------- per-chunk partial sums (64-pt chunks)
__global__ __launch_bounds__(128) void scan_chunk(
    const float* __restrict__ x, const int* __restrict__ perm,
    const float* __restrict__ g, const float* __restrict__ dvs,
    double* __restrict__ chunkU, double* __restrict__ chunkGU) {
    int b = blockIdx.x, ch = blockIdx.y, c = threadIdx.x;
    __shared__ int   pidx[64];
    __shared__ float gl[64], dl[64];
    int t0 = ch * 64;
    if (c < 64) {
        pidx[c] = perm[b * M_ + t0 + c];
        gl[c]   = g[t0 + c];
        dl[c]   = dvs[t0 + c];
    }
    __syncthreads();
    const float* xb = x + (size_t)b * M_ * C_;
    double sU = 0.0, sGU = 0.0;
    #pragma unroll 4
    for (int tt = 0; tt < 64; ++tt) {
        double u = (double)xb[(size_t)pidx[tt] * C_ + c] * (double)dl[tt];
        sU  += u;
        sGU += (double)gl[tt] * u;
    }
    chunkU [(size_t)(b * 32 + ch) * 128 + c] = sU;
    chunkGU[(size_t)(b * 32 + ch) * 128 + c] = sGU;
}

// ---------------------------------------------------------------- y via two prefix scans
__global__ __launch_bounds__(128) void scan_final(
    const float* __restrict__ x, const int* __restrict__ perm,
    const float* __restrict__ g, const float* __restrict__ dvs,
    const double* __restrict__ chunkU, const double* __restrict__ chunkGU,
    float* __restrict__ y) {
    int b = blockIdx.x, ch = blockIdx.y, c = threadIdx.x;
    __shared__ int   pidx[64];
    __shared__ float gl[64], dl[64];
    int t0 = ch * 64;
    if (c < 64) {
        pidx[c] = perm[b * M_ + t0 + c];
        gl[c]   = g[t0 + c];
        dl[c]   = dvs[t0 + c];
    }
    __syncthreads();
    double Utot = 0.0, runU = 0.0, runG = 0.0;
    #pragma unroll 4
    for (int q = 0; q < 32; ++q) {
        double cu = chunkU[(size_t)(b * 32 + q) * 128 + c];
        Utot += cu;
        if (q < ch) { runU += cu; runG += chunkGU[(size_t)(b * 32 + q) * 128 + c]; }
    }
    const float* xb = x + (size_t)b * M_ * C_;
    float*       yb = y + (size_t)b * M_ * C_;
    #pragma unroll 2
    for (int tt = 0; tt < 64; ++tt) {
        int idx = pidx[tt];
        double u  = (double)xb[(size_t)idx * C_ + c] * (double)dl[tt];
        double yv = (double)dl[tt] * ((double)gl[tt] * (Utot - runU) + runG);
        yb[(size_t)idx * C_ + c] = (float)yv;
        runU += u;
        runG += (double)gl[tt] * u;
    }
}

// ---------------------------------------------------------------- out = SiLU(y @ W^T), in-place
__global__ __launch_bounds__(256, 2) void linear_silu(float* __restrict__ y,
                                                      const float* __restrict__ W) {
    int b = blockIdx.y, m0 = blockIdx.x * 64;
    __shared__ f4 Y4[64][32];
    __shared__ f4 W4[64][32];
    float* yb = y + ((size_t)b * M_ + m0) * C_;
    int tid = threadIdx.x;
    for (int s = tid; s < 64 * 32; s += 256) {
        int row = s >> 5, c4 = s & 31;
        Y4[row][c4 ^ (row & 31)] = ((const f4*)(yb + (size_t)row * C_))[c4];
    }
    int tx = tid & 15, ty = tid >> 4;
    for (int half = 0; half < 2; ++half) {
        __syncthreads();
        for (int s = tid; s < 64 * 32; s += 256) {
            int row = s >> 5, c4 = s & 31;
            W4[row][c4 ^ (row & 31)] = ((const f4*)(W + (size_t)(half * 64 + row) * C_))[c4];
        }
        __syncthreads();
        float acc[4][4] = {};
        #pragma unroll 4
        for (int k4 = 0; k4 < 32; ++k4) {
            f4 a[4], w[4];
            #pragma unroll
            for (int d = 0; d < 4; ++d) {
                int rm = ty + 16 * d;
                a[d] = Y4[rm][k4 ^ (rm & 31)];
                int rc = tx + 16 * d;
                w[d] = W4[rc][k4 ^ (rc & 31)];
            }
            #pragma unroll
            for (int di = 0; di < 4; ++di)
                #pragma unroll
                for (int dj = 0; dj < 4; ++dj)
                    acc[di][dj] += a[di].x * w[dj].x + a[di].y * w[dj].y +
                                   a[di].z * w[dj].z + a[di].w * w[dj].w;
        }
        #pragma unroll
        for (int di = 0; di < 4; ++di)
            #pragma unroll
            for (int dj = 0; dj < 4; ++dj) {
                int m = ty + 16 * di, co = half * 64 + tx + 16 * dj;
                float v = acc[di][dj];
                yb[(size_t)m * C_ + co] = v / (1.f + __expf(-v));
            }
    }
}

// ----------------------------------------------------------------
extern "C" void kernel_launch(void* const* d_in, const int* in_sizes, int n_in,
                              void* d_out, int out_size, void* d_ws, size_t ws_size,
                              hipStream_t stream) {
    (void)in_sizes; (void)n_in; (void)out_size; (void)ws_size;
    const float* x = (const float*)d_in[0];
    const float* W = (const float*)d_in[1];
    float* out = (float*)d_out;

    char* ws = (char*)d_ws;
    size_t o = 0;
    auto alloc = [&](size_t n) { size_t r = o; o += (n + 255) & ~(size_t)255; return r; };
    double* off_part = (double*)(ws + alloc((size_t)B_ * 16 * 8));
    float*  invh     = (float*) (ws + alloc(B_ * 4));
    float*  sqv      = (float*) (ws + alloc((size_t)B_ * M_ * 4));        // 128KB
    float*  rho      = (float*) (ws + alloc((size_t)B_ * M_ * 4));        // 128KB
    int*    perm     = (int*)   (ws + alloc((size_t)B_ * M_ * 4));        // 128KB
    float*  g        = (float*) (ws + alloc(M_ * 4));
    float*  dvs      = (float*) (ws + alloc(M_ * 4));
    double* chunkU   = (double*)(ws + alloc((size_t)B_ * 32 * C_ * 8));   // 512KB
    double* chunkGU  = (double*)(ws + alloc((size_t)B_ * 32 * C_ * 8));   // 512KB
    // xhi/xlo bf16 (8MB each) live in d_out; consumed by grams before y is written.
    char* xhi = (char*)d_out;
    char* xlo = xhi + (size_t)B_ * M_ * 256;

    prep_kernel<<<(B_ * M_) / 8, 256, 0, stream>>>(x, (uint2*)xhi, (uint2*)xlo, sqv);
    gram_mfma<0><<<256, 512, 0, stream>>>(xhi, xlo, sqv, nullptr, off_part, nullptr);
    small_kernel<<<2, 256, 0, stream>>>(off_part, invh, g, dvs);
    gram_mfma<1><<<256, 512, 0, stream>>>(xhi, xlo, sqv, invh, nullptr, rho);
    rank_kernel<<<dim3(M_ / 128, B_), 128, 0, stream>>>(rho, perm);
    scan_chunk<<<dim3(B_, 32), 128, 0, stream>>>(x, perm, g, dvs, chunkU, chunkGU);
    scan_final<<<dim3(B_, 32), 128, 0, stream>>>(x, perm, g, dvs, chunkU, chunkGU, out);
    linear_silu<<<dim3(M_ / 64, B_), 256, 0, stream>>>(out, W);
}

// Round 5
// 225.743 us; speedup vs baseline: 3.3734x; 1.0089x over previous
//
#include <hip/hip_runtime.h>
#include <math.h>

#define B_ 16
#define M_ 2048
#define C_ 128

using f4 = float4;
typedef __attribute__((ext_vector_type(8))) short bf16x8;
typedef __attribute__((ext_vector_type(16))) float f32x16;

// round-to-nearest-even f32 -> bf16 bits
__device__ inline unsigned short bfr(float f) {
    unsigned int u = __float_as_uint(f);
    return (unsigned short)((u + 0x7FFFu + ((u >> 16) & 1u)) >> 16);
}

// ---------------------------------------------------------------- x -> xhi, xlo (bf16), sq
__global__ __launch_bounds__(256) void prep_kernel(const float* __restrict__ x,
                                                   uint2* __restrict__ xhi,
                                                   uint2* __restrict__ xlo,
                                                   float* __restrict__ sq) {
    int wid = threadIdx.x >> 6, lane = threadIdx.x & 63;
    int l31 = lane & 31, l5 = lane >> 5;
    int row = blockIdx.x * 8 + wid * 2 + l5;
    f4 v = ((const f4*)(x + (size_t)row * C_))[l31];
    unsigned short h0 = bfr(v.x), h1 = bfr(v.y), h2 = bfr(v.z), h3 = bfr(v.w);
    float r0 = v.x - __uint_as_float((unsigned)h0 << 16);
    float r1 = v.y - __uint_as_float((unsigned)h1 << 16);
    float r2 = v.z - __uint_as_float((unsigned)h2 << 16);
    float r3 = v.w - __uint_as_float((unsigned)h3 << 16);
    unsigned short l0 = bfr(r0), l1 = bfr(r1), l2 = bfr(r2), l3 = bfr(r3);
    uint2 hp, lp;
    hp.x = (unsigned)h0 | ((unsigned)h1 << 16);
    hp.y = (unsigned)h2 | ((unsigned)h3 << 16);
    lp.x = (unsigned)l0 | ((unsigned)l1 << 16);
    lp.y = (unsigned)l2 | ((unsigned)l3 << 16);
    xhi[(size_t)row * 32 + l31] = hp;          // 256B per row
    xlo[(size_t)row * 32 + l31] = lp;
    float dot = v.x * v.x + v.y * v.y + v.z * v.z + v.w * v.w;
    #pragma unroll
    for (int m = 1; m < 32; m <<= 1) dot += __shfl_xor(dot, m);
    if (l31 == 0) sq[row] = dot;
}

// ---------------------------------------------------------------- persistent-panel MFMA Gram
// Prefetch hoisted to step top (full-step flight time before the vmcnt(0) drain).
// MODE 0: hi*hi -> off-diag dist sum; grid 512 (j-sweep split in 2), 4 waves/SIMD.
// MODE 1: hi*hi+hi*lo+lo*hi -> rho direct; grid 256.
template <int MODE>
__global__ __launch_bounds__(512, MODE == 0 ? 4 : 2) void gram_mfma(
    const char* __restrict__ xhi, const char* __restrict__ xlo,
    const float* __restrict__ sq, const float* __restrict__ invh,
    double* __restrict__ off_part, float* __restrict__ rho) {
    constexpr int TB = (MODE == 1) ? 65536 : 32768;   // per-buffer bytes (hi[+lo])
    constexpr int NS = (MODE == 1) ? 16 : 8;          // j-panel steps per block
    __shared__ __align__(16) char lds[2 * TB];
    __shared__ float sqs[128];                        // MODE0: A-panel sq broadcast slab
    int tid = threadIdx.x, lane = tid & 63, wid = tid >> 6;
    int l31 = lane & 31, l5 = lane >> 5;
    int wr = wid >> 2, wc = wid & 3;                  // wave tile: rows wr*64(+64), cols wc*32
    int bid = blockIdx.x;
    int b, ip, jp0;
    if (MODE == 1) {
        int swz = (bid & 7) * 32 + (bid >> 3);        // bijective XCD swizzle (256 = 8*32)
        b = swz >> 4; ip = swz & 15; jp0 = 0;
    } else {
        int swz = (bid & 7) * 64 + (bid >> 3);        // bijective XCD swizzle (512 = 8*64)
        b = swz >> 5; ip = (swz >> 1) & 15; jp0 = (swz & 1) * 8;
    }
    const char* hbase = xhi + (size_t)b * M_ * 256;
    const char* lbase = xlo + (size_t)b * M_ * 256;
    char* buf0 = lds;
    char* buf1 = lds + TB;

    // one 1KB global_load_lds slice (inst q of 4 per wave) of a 32KB panel tile
    auto stage1 = [&](const char* src, char* dst, int q) {
        int inst = wid * 4 + q;
        int row  = inst * 4 + (lane >> 4);
        int ch   = (lane & 15) ^ (row & 15);
        __builtin_amdgcn_global_load_lds(
            (const __attribute__((address_space(1))) unsigned int*)(src + row * 256 + ch * 16),
            (__attribute__((address_space(3))) unsigned int*)(dst + inst * 1024),
            16, 0, 0);
    };
    auto stageAll = [&](const char* src, char* dst) {
        #pragma unroll
        for (int q = 0; q < 4; ++q) stage1(src, dst, q);
    };

    // prologue: A panel -> buf1 -> registers; then B[jp0] -> buf0
    stageAll(hbase + (size_t)ip * 32768, buf1);
    if (MODE == 1) stageAll(lbase + (size_t)ip * 32768, buf1 + 32768);
    if (MODE == 0 && tid < 128) sqs[tid] = sq[b * M_ + ip * 128 + tid];
    __syncthreads();
    bf16x8 ahi[2][8], alo[2][8];
    #pragma unroll
    for (int fi = 0; fi < 2; ++fi)
        #pragma unroll
        for (int ks = 0; ks < 8; ++ks) {
            int row = wr * 64 + fi * 32 + l31;
            int ch  = ((ks << 1) | l5) ^ (row & 15);
            ahi[fi][ks] = *(const bf16x8*)(buf1 + row * 256 + ch * 16);
            if (MODE == 1)
                alo[fi][ks] = *(const bf16x8*)(buf1 + 32768 + row * 256 + ch * 16);
        }
    // A-frag ds_reads must complete before panel jp0+1 DMA overwrites buf1
    // (issued after the first in-loop barrier) -> drain lgkm here.
    asm volatile("s_waitcnt lgkmcnt(0)" ::: "memory");
    __builtin_amdgcn_sched_barrier(0);
    stageAll(hbase + (size_t)jp0 * 32768, buf0);
    if (MODE == 1) stageAll(lbase + (size_t)jp0 * 32768, buf0 + 32768);

    float svh = 0.f;
    if (MODE == 1) svh = invh[b] * 1.4426950408889634f;   // s * log2(e)
    float c2 = 2.f * svh;
    f32x16 rs0 = {}, rs1 = {};
    float part = 0.f;

    #pragma unroll 1
    for (int s = 0; s < NS; ++s) {
        char* cur = (s & 1) ? buf1 : buf0;
        char* nxt = (s & 1) ? buf0 : buf1;
        // boundary: my step-(s-1) ds_reads done (nxt safe to overwrite), panel s resident,
        // then barrier -> all waves agree before any DMA into nxt is issued.
        asm volatile("s_waitcnt lgkmcnt(0)" ::: "memory");
        asm volatile("s_waitcnt vmcnt(0)" ::: "memory");
        __builtin_amdgcn_s_barrier();
        if (s < NS - 1) {                             // hoisted prefetch: full step in flight
            const char* hs = hbase + (size_t)(jp0 + s + 1) * 32768;
            stageAll(hs, nxt);
            if (MODE == 1) {
                const char* ls = lbase + (size_t)(jp0 + s + 1) * 32768;
                stageAll(ls, nxt + 32768);
            }
        }
        float sqj = sq[b * M_ + (jp0 + s) * 128 + wc * 32 + l31];
        f32x16 acc0 = {}, acc1 = {};
        #pragma unroll
        for (int p = 0; p < 4; ++p) {                 // 2 k-slices per phase
            int brow = wc * 32 + l31;
            int ks0 = 2 * p;
            int ch0 = ((ks0 << 1) | l5) ^ (brow & 15);
            int ch1 = (((ks0 + 1) << 1) | l5) ^ (brow & 15);
            bf16x8 bh0 = *(const bf16x8*)(cur + brow * 256 + ch0 * 16);
            bf16x8 bh1 = *(const bf16x8*)(cur + brow * 256 + ch1 * 16);
            bf16x8 bl0, bl1;
            if (MODE == 1) {
                bl0 = *(const bf16x8*)(cur + 32768 + brow * 256 + ch0 * 16);
                bl1 = *(const bf16x8*)(cur + 32768 + brow * 256 + ch1 * 16);
            }
            __builtin_amdgcn_s_setprio(1);
            acc0 = __builtin_amdgcn_mfma_f32_32x32x16_bf16(ahi[0][ks0], bh0, acc0, 0, 0, 0);
            acc1 = __builtin_amdgcn_mfma_f32_32x32x16_bf16(ahi[1][ks0], bh0, acc1, 0, 0, 0);
            acc0 = __builtin_amdgcn_mfma_f32_32x32x16_bf16(ahi[0][ks0 + 1], bh1, acc0, 0, 0, 0);
            acc1 = __builtin_amdgcn_mfma_f32_32x32x16_bf16(ahi[1][ks0 + 1], bh1, acc1, 0, 0, 0);
            if (MODE == 1) {
                acc0 = __builtin_amdgcn_mfma_f32_32x32x16_bf16(alo[0][ks0], bh0, acc0, 0, 0, 0);
                acc1 = __builtin_amdgcn_mfma_f32_32x32x16_bf16(alo[1][ks0], bh0, acc1, 0, 0, 0);
                acc0 = __builtin_amdgcn_mfma_f32_32x32x16_bf16(ahi[0][ks0], bl0, acc0, 0, 0, 0);
                acc1 = __builtin_amdgcn_mfma_f32_32x32x16_bf16(ahi[1][ks0], bl0, acc1, 0, 0, 0);
                acc0 = __builtin_amdgcn_mfma_f32_32x32x16_bf16(alo[0][ks0 + 1], bh1, acc0, 0, 0, 0);
                acc1 = __builtin_amdgcn_mfma_f32_32x32x16_bf16(alo[1][ks0 + 1], bh1, acc1, 0, 0, 0);
                acc0 = __builtin_amdgcn_mfma_f32_32x32x16_bf16(ahi[0][ks0 + 1], bl1, acc0, 0, 0, 0);
                acc1 = __builtin_amdgcn_mfma_f32_32x32x16_bf16(ahi[1][ks0 + 1], bl1, acc1, 0, 0, 0);
            }
            __builtin_amdgcn_s_setprio(0);
        }
        if (MODE == 1) {
            float m = -sqj * svh;
            #pragma unroll
            for (int rg = 0; rg < 16; ++rg) {
                rs0[rg] += exp2f(fmaf(acc0[rg], c2, m));
                rs1[rg] += exp2f(fmaf(acc1[rg], c2, m));
            }
        } else {
            bool dg = ((jp0 + s) == ip);
            int colt = wc * 32 + l31;
            #pragma unroll
            for (int rg = 0; rg < 16; ++rg) {
                int rl = (rg & 3) + ((rg >> 2) << 3) + (l5 << 2);
                float si0 = sqs[wr * 64 + rl];
                float si1 = sqs[wr * 64 + 32 + rl];
                float d0 = si0 + sqj - 2.f * acc0[rg];
                float d1 = si1 + sqj - 2.f * acc1[rg];
                float s0 = sqrtf(fmaxf(d0, 1e-12f));
                float s1 = sqrtf(fmaxf(d1, 1e-12f));
                if (dg && (wr * 64 + rl) == colt) s0 = 0.f;
                if (dg && (wr * 64 + 32 + rl) == colt) s1 = 0.f;
                part += s0 + s1;
            }
        }
    }

    if (MODE == 1) {
        #pragma unroll
        for (int rg = 0; rg < 16; ++rg) {
            float v0 = rs0[rg], v1 = rs1[rg];
            #pragma unroll
            for (int m = 1; m < 32; m <<= 1) { v0 += __shfl_xor(v0, m); v1 += __shfl_xor(v1, m); }
            rs0[rg] = v0; rs1[rg] = v1;
        }
        __syncthreads();
        float* scr = (float*)lds;                     // [wc][128]
        if (l31 == 0) {
            #pragma unroll
            for (int rg = 0; rg < 16; ++rg) {
                int r0 = wr * 64 + (rg & 3) + ((rg >> 2) << 3) + (l5 << 2);
                scr[wc * 128 + r0]      = rs0[rg];
                scr[wc * 128 + r0 + 32] = rs1[rg];
            }
        }
        __syncthreads();
        if (tid < 128) {
            int pt = b * M_ + ip * 128 + tid;
            float tot = scr[tid] + scr[128 + tid] + scr[256 + tid] + scr[384 + tid];
            rho[pt] = exp2f(-sq[pt] * svh) * tot;
        }
    } else {
        #pragma unroll
        for (int m = 1; m < 64; m <<= 1) part += __shfl_xor(part, m);
        __syncthreads();
        double* dscr = (double*)lds;
        if (lane == 0) dscr[wid] = (double)part;
        __syncthreads();
        if (tid == 0) {
            double t = 0.0;
            #pragma unroll
            for (int w = 0; w < 8; ++w) t += dscr[w];
            off_part[b * 32 + ip * 2 + (jp0 >> 3)] = t;
        }
    }
}

// ---------------------------------------------------------------- fused: invh (block 0) + g/dvs (block 1)
__global__ __launch_bounds__(256) void small_kernel(const double* __restrict__ op,
                                                    float* __restrict__ invh,
                                                    float* __restrict__ g,
                                                    float* __restrict__ dvs) {
    int tid = threadIdx.x;
    if (blockIdx.x == 0) {
        int b = tid >> 4, k = tid & 15;
        double v = op[b * 32 + k] + op[b * 32 + 16 + k];
        #pragma unroll
        for (int m = 1; m < 16; m <<= 1) v += __shfl_xor(v, m);
        if (k == 0) {
            double h = v / ((double)M_ * (double)(M_ - 1));
            h = h > 1e-6 ? h : 1e-6;
            invh[b] = (float)(1.0 / (2.0 * h * h));
        }
    } else {
        __shared__ double w[256];
        double loc = 0.0;
        #pragma unroll
        for (int q = 0; q < 8; ++q) loc += 1.0 / (double)(M_ - (tid * 8 + q));
        w[tid] = loc; __syncthreads();
        for (int o = 1; o < 256; o <<= 1) {
            double v = (tid >= o) ? w[tid - o] : 0.0;
            __syncthreads();
            w[tid] += v;
            __syncthreads();
        }
        double acc = (tid > 0) ? w[tid - 1] : 0.0;
        #pragma unroll
        for (int q = 0; q < 8; ++q) {
            int t = tid * 8 + q;
            acc += 1.0 / (double)(M_ - t);
            g[t]   = (float)acc;
            dvs[t] = (float)(1.0 / sqrt((double)(t + 1)));
        }
    }
}

// ---------------------------------------------------------------- rank + scatter permutation
__global__ __launch_bounds__(128) void rank_kernel(const float* __restrict__ rho,
                                                   int* __restrict__ perm) {
    int b = blockIdx.y;
    int i = blockIdx.x * 128 + threadIdx.x;
    __shared__ float r[M_];
    const float* rb = rho + b * M_;
    for (int t = threadIdx.x; t < M_; t += 128) r[t] = rb[t];
    __syncthreads();
    float rv = r[i];
    int cnt = 0;
    #pragma unroll 4
    for (int j = 0; j < M_; ++j) {
        float o = r[j];
        cnt += (o < rv || (o == rv && j < i)) ? 1 : 0;
    }
    perm[b * M_ + cnt] = i;
}

// ---------------------------------------------------------------- per-chunk partial sums (64-pt chunks)
__global__ __launch_bounds__(128) void scan_chunk(
    const float* __restrict__ x, const int* __restrict__ perm,
    const float* __restrict__ g, const float* __restrict__ dvs,
    double* __restrict__ chunkU, double* __restrict__ chunkGU) {
    int b = blockIdx.x, ch = blockIdx.y, c = threadIdx.x;
    __shared__ int   pidx[64];
    __shared__ float gl[64], dl[64];
    int t0 = ch * 64;
    if (c < 64) {
        pidx[c] = perm[b * M_ + t0 + c];
        gl[c]   = g[t0 + c];
        dl[c]   = dvs[t0 + c];
    }
    __syncthreads();
    const float* xb = x + (size_t)b * M_ * C_;
    double sU = 0.0, sGU = 0.0;
    #pragma unroll 4
    for (int tt = 0; tt < 64; ++tt) {
        double u = (double)xb[(size_t)pidx[tt] * C_ + c] * (double)dl[tt];
        sU  += u;
        sGU += (double)gl[tt] * u;
    }
    chunkU [(size_t)(b * 32 + ch) * 128 + c] = sU;
    chunkGU[(size_t)(b * 32 + ch) * 128 + c] = sGU;
}

// ---------------------------------------------------------------- y via two prefix scans
__global__ __launch_bounds__(128) void scan_final(
    const float* __restrict__ x, const int* __restrict__ perm,
    const float* __restrict__ g, const float* __restrict__ dvs,
    const double* __restrict__ chunkU, const double* __restrict__ chunkGU,
    float* __restrict__ y) {
    int b = blockIdx.x, ch = blockIdx.y, c = threadIdx.x;
    __shared__ int   pidx[64];
    __shared__ float gl[64], dl[64];
    int t0 = ch * 64;
    if (c < 64) {
        pidx[c] = perm[b * M_ + t0 + c];
        gl[c]   = g[t0 + c];
        dl[c]   = dvs[t0 + c];
    }
    __syncthreads();
    double Utot = 0.0, runU = 0.0, runG = 0.0;
    #pragma unroll 4
    for (int q = 0; q < 32; ++q) {
        double cu = chunkU[(size_t)(b * 32 + q) * 128 + c];
        Utot += cu;
        if (q < ch) { runU += cu; runG += chunkGU[(size_t)(b * 32 + q) * 128 + c]; }
    }
    const float* xb = x + (size_t)b * M_ * C_;
    float*       yb = y + (size_t)b * M_ * C_;
    #pragma unroll 2
    for (int tt = 0; tt < 64; ++tt) {
        int idx = pidx[tt];
        double u  = (double)xb[(size_t)idx * C_ + c] * (double)dl[tt];
        double yv = (double)dl[tt] * ((double)gl[tt] * (Utot - runU) + runG);
        yb[(size_t)idx * C_ + c] = (float)yv;
        runU += u;
        runG += (double)gl[tt] * u;
    }
}

// ---------------------------------------------------------------- out = SiLU(y @ W^T), in-place
__global__ __launch_bounds__(256, 2) void linear_silu(float* __restrict__ y,
                                                      const float* __restrict__ W) {
    int b = blockIdx.y, m0 = blockIdx.x * 64;
    __shared__ f4 Y4[64][32];
    __shared__ f4 W4[64][32];
    float* yb = y + ((size_t)b * M_ + m0) * C_;
    int tid = threadIdx.x;
    for (int s = tid; s < 64 * 32; s += 256) {
        int row = s >> 5, c4 = s & 31;
        Y4[row][c4 ^ (row & 31)] = ((const f4*)(yb + (size_t)row * C_))[c4];
    }
    int tx = tid & 15, ty = tid >> 4;
    for (int half = 0; half < 2; ++half) {
        __syncthreads();
        for (int s = tid; s < 64 * 32; s += 256) {
            int row = s >> 5, c4 = s & 31;
            W4[row][c4 ^ (row & 31)] = ((const f4*)(W + (size_t)(half * 64 + row) * C_))[c4];
        }
        __syncthreads();
        float acc[4][4] = {};
        #pragma unroll 4
        for (int k4 = 0; k4 < 32; ++k4) {
            f4 a[4], w[4];
            #pragma unroll
            for (int d = 0; d < 4; ++d) {
                int rm = ty + 16 * d;
                a[d] = Y4[rm][k4 ^ (rm & 31)];
                int rc = tx + 16 * d;
                w[d] = W4[rc][k4 ^ (rc & 31)];
            }
            #pragma unroll
            for (int di = 0; di < 4; ++di)
                #pragma unroll
                for (int dj = 0; dj < 4; ++dj)
                    acc[di][dj] += a[di].x * w[dj].x + a[di].y * w[dj].y +
                                   a[di].z * w[dj].z + a[di].w * w[dj].w;
        }
        #pragma unroll
        for (int di = 0; di < 4; ++di)
            #pragma unroll
            for (int dj = 0; dj < 4; ++dj) {
                int m = ty + 16 * di, co = half * 64 + tx + 16 * dj;
                float v = acc[di][dj];
                yb[(size_t)m * C_ + co] = v / (1.f + __expf(-v));
            }
    }
}

// ----------------------------------------------------------------
extern "C" void kernel_launch(void* const* d_in, const int* in_sizes, int n_in,
                              void* d_out, int out_size, void* d_ws, size_t ws_size,
                              hipStream_t stream) {
    (void)in_sizes; (void)n_in; (void)out_size; (void)ws_size;
    const float* x = (const float*)d_in[0];
    const float* W = (const float*)d_in[1];
    float* out = (float*)d_out;

    char* ws = (char*)d_ws;
    size_t o = 0;
    auto alloc = [&](size_t n) { size_t r = o; o += (n + 255) & ~(size_t)255; return r; };
    double* off_part = (double*)(ws + alloc((size_t)B_ * 32 * 8));
    float*  invh     = (float*) (ws + alloc(B_ * 4));
    float*  sqv      = (float*) (ws + alloc((size_t)B_ * M_ * 4));        // 128KB
    float*  rho      = (float*) (ws + alloc((size_t)B_ * M_ * 4));        // 128KB
    int*    perm     = (int*)   (ws + alloc((size_t)B_ * M_ * 4));        // 128KB
    float*  g        = (float*) (ws + alloc(M_ * 4));
    float*  dvs      = (float*) (ws + alloc(M_ * 4));
    double* chunkU   = (double*)(ws + alloc((size_t)B_ * 32 * C_ * 8));   // 512KB
    double* chunkGU  = (double*)(ws + alloc((size_t)B_ * 32 * C_ * 8));   // 512KB
    // xhi/xlo bf16 (8MB each) live in d_out; consumed by grams before y is written.
    char* xhi = (char*)d_out;
    char* xlo = xhi + (size_t)B_ * M_ * 256;

    prep_kernel<<<(B_ * M_) / 8, 256, 0, stream>>>(x, (uint2*)xhi, (uint2*)xlo, sqv);
    gram_mfma<0><<<512, 512, 0, stream>>>(xhi, xlo, sqv, nullptr, off_part, nullptr);
    small_kernel<<<2, 256, 0, stream>>>(off_part, invh, g, dvs);
    gram_mfma<1><<<256, 512, 0, stream>>>(xhi, xlo, sqv, invh, nullptr, rho);
    rank_kernel<<<dim3(M_ / 128, B_), 128, 0, stream>>>(rho, perm);
    scan_chunk<<<dim3(B_, 32), 128, 0, stream>>>(x, perm, g, dvs, chunkU, chunkGU);
    scan_final<<<dim3(B_, 32), 128, 0, stream>>>(x, perm, g, dvs, chunkU, chunkGU, out);
    linear_silu<<<dim3(M_ / 64, B_), 256, 0, stream>>>(out, W);
}